// Round 22
// baseline (623.079 us; speedup 1.0000x reference)
//
#include <hip/hip_runtime.h>
#include <math.h>

#define BN_EPS 1e-5f
typedef unsigned long long u64;
typedef __attribute__((ext_vector_type(8))) short bf16x8;
typedef __attribute__((ext_vector_type(8))) unsigned short u16x8;
typedef __attribute__((ext_vector_type(4))) float f32x4;

// mish(x) = x*tanh(ln(1+e^x)) = x*w/(w+2), w = u(u+2), u = e^x (clamped).
__device__ __forceinline__ float mishf(float x){
  float u = __expf(fminf(x, 20.f));
  float w = u * (u + 2.f);
  return x * w / (w + 2.f);
}

__device__ __forceinline__ unsigned fenc(float f){
  unsigned u = __float_as_uint(f);
  return u ^ ((unsigned)((int)u >> 31) | 0x80000000u);
}
__device__ __forceinline__ float fdec(unsigned e){
  unsigned u = (e & 0x80000000u) ? (e & 0x7fffffffu) : ~e;
  return __uint_as_float(u);
}

// bf16x3 split: a = hi + lo (+O(2^-17 a)); rne via bit trick
__device__ __forceinline__ void bfsplit(float a, unsigned short &h, unsigned short &l){
  unsigned u = __float_as_uint(a);
  unsigned hb = (u + 0x7FFFu + ((u >> 16) & 1u)) >> 16;
  h = (unsigned short)hb;
  float hf = __uint_as_float(hb << 16);
  float r = a - hf;
  unsigned v = __float_as_uint(r);
  l = (unsigned short)((v + 0x7FFFu + ((v >> 16) & 1u)) >> 16);
}

// packed key: (value desc, index asc) == lax.top_k order as single u64 compare
__device__ __forceinline__ u64 mkkey(float v, int i){
  return ((u64)fenc(v) << 32) | (unsigned)(~i);
}
__device__ __forceinline__ int keyidx(u64 k){ return (int)(~(unsigned)k); }

__device__ __forceinline__ void ins10k(u64 (&L)[10], u64 k){
  if (k <= L[9]) return;
  #pragma unroll
  for (int p = 9; p >= 1; --p)
    L[p] = (k > L[p-1]) ? L[p-1] : ((k > L[p]) ? k : L[p]);
  L[0] = (k > L[0]) ? k : L[0];
}

// branchless score-only insert into sorted-desc u32 list: 9x v_med3_u32 + max.
__device__ __forceinline__ void ins10s(unsigned (&S)[10], unsigned e){
  #pragma unroll
  for (int p = 9; p >= 1; --p){
    unsigned ns;
    asm("v_med3_u32 %0, %1, %2, %3" : "=v"(ns) : "v"(e), "v"(S[p-1]), "v"(S[p]));
    S[p] = ns;
  }
  S[0] = (e > S[0]) ? e : S[0];
}

// u32 dual-list gated push: sorted scores S (encoded desc) + parallel indices I.
// Strict e>th + ascending per-lane stream indices == exact (value desc, idx asc)
// order of the u64 key scheme (ties always lose to the resident/earlier index).
#define TOPK_INIT(S, I, eth) do { \
  _Pragma("unroll") \
  for (int _j = 0; _j < 10; ++_j) { S[_j] = 0x007FFFFFu; I[_j] = 0x7fffffffu; } \
  eth = 0x007FFFFFu; } while (0)

__device__ __forceinline__ void topk_push32(unsigned (&S)[10], unsigned (&I)[10],
                                            unsigned &eth, float v, unsigned i){
  unsigned e = fenc(v);
  if (e > eth) {
    #pragma unroll
    for (int p = 9; p >= 1; --p) {
      bool gp = e > S[p-1];
      bool gc = e > S[p];
      I[p] = gp ? I[p-1] : (gc ? i : I[p]);
      unsigned ns;
      asm("v_med3_u32 %0, %1, %2, %3" : "=v"(ns) : "v"(e), "v"(S[p-1]), "v"(S[p]));
      S[p] = ns;
    }
    bool g0 = e > S[0];
    I[0] = g0 ? i : I[0];
    S[0] = g0 ? e : S[0];
    eth = S[9];
  }
}

// snapshot-butterfly merge of sorted-desc u32 score lists across lanes
__device__ __forceinline__ void wavemerge10(unsigned (&S)[10], int mask){
  unsigned T[10];
  #pragma unroll
  for (int j = 0; j < 10; ++j) T[j] = __shfl_xor(S[j], mask);
  #pragma unroll
  for (int j = 0; j < 10; ++j) ins10s(S, T[j]);
}

// snapshot-butterfly merge of exact u64 key lists across lanes (snapshot
// partner's FULL list first; lockstep in-place merge would read partially
// merged data -> duplicates).
__device__ __forceinline__ void wavemerge10k(u64 (&L)[10], int mask){
  u64 T[10];
  #pragma unroll
  for (int j = 0; j < 10; ++j) T[j] = __shfl_xor(L[j], mask);
  #pragma unroll
  for (int j = 0; j < 10; ++j) ins10k(L, T[j]);
}
#define KSENT mkkey(-INFINITY, 0x7fffffff)

__global__ void k_diag(float* __restrict__ out, float v){ out[0] = v; }

__global__ __launch_bounds__(256)
void k_zero(unsigned* __restrict__ p){
  p[blockIdx.x * 256 + threadIdx.x] = 0u;      // 32 blocks -> 8192
}

// ---------- knn C=3 from x [B,3,N]: TWO-PASS, 16 points/block, 16 chunks ----------
// (r18 form, verified: LDS-staged pass 1, wave-butterfly, global rescan pass 2)
__global__ __launch_bounds__(256)
void k_knn3(const float* __restrict__ x, int* __restrict__ idxout){
  __shared__ __align__(16) char smem[33024];
  float4* pts4   = (float4*)smem;                    // [16][129] (pass 1 only)
  unsigned* m1u  = (unsigned*)smem;                  // [4][10][16] = 2560 B
  unsigned* thr  = (unsigned*)(smem + 2560);         // [16]
  int*      cnt  = (int*)(smem + 2624);              // [16]
  u64*      buf  = (u64*)(smem + 2688);              // [16][16] = 2048 B
  const int t  = threadIdx.x;
  const int b  = blockIdx.x >> 7;                    // 1024 blocks: 128 per batch
  const int p0 = (blockIdx.x & 127) * 16;
  const int pt = t & 15, ch = t >> 4;
  const float* xb = x + (size_t)b * 6144;

  for (int i = t; i < 2048; i += 256) {
    float x0 = xb[i], x1 = xb[2048 + i], x2 = xb[4096 + i];
    float s2 = x0 * x0; s2 = fmaf(x1, x1, s2); s2 = fmaf(x2, x2, s2);
    pts4[(i >> 7) * 129 + (i & 127)] = make_float4(x0, x1, x2, s2);
  }
  __syncthreads();

  const int g = p0 + pt;
  const float4 ov = pts4[(g >> 7) * 129 + (g & 127)];
  unsigned S[10];
  #pragma unroll
  for (int j = 0; j < 10; ++j) S[j] = 0x007FFFFFu;   // fenc(-inf)
  const float4* cp = pts4 + ch * 129;
  #pragma unroll 4
  for (int j = 0; j < 128; ++j) {
    float4 pv = cp[j];
    float dot = ov.x * pv.x; dot = fmaf(ov.y, pv.y, dot); dot = fmaf(ov.z, pv.z, dot);
    float key = fmaf(2.f, dot, -ov.w) - pv.w;
    ins10s(S, fenc(key));
  }
  // merge the 4 chunks resident in this wave (lane bits 4,5 = ch&3)
  wavemerge10(S, 16);
  wavemerge10(S, 32);
  __syncthreads();                                   // pts4 reads done; overlay

  if ((t & 48) == 0) {                               // one lane per (wave, pt)
    int wv = t >> 6;
    #pragma unroll
    for (int j = 0; j < 10; ++j)
      m1u[(wv * 10 + j) * 16 + pt] = S[j];
  }
  __syncthreads();

  if (t < 16) {                                      // final threshold per point
    unsigned F[10];
    #pragma unroll
    for (int j = 0; j < 10; ++j) F[j] = 0x007FFFFFu;
    for (int wv = 0; wv < 4; ++wv)
      #pragma unroll
      for (int j = 0; j < 10; ++j)
        ins10s(F, m1u[(wv * 10 + j) * 16 + t]);
    thr[t] = F[9];
    cnt[t] = 0;
  }
  __syncthreads();

  // pass 2: rescan from global; recompute keys BIT-IDENTICALLY (same chains)
  const unsigned th = thr[pt];
  for (int j = 0; j < 128; ++j) {
    int c = ch * 128 + j;
    float x0 = xb[c], x1 = xb[2048 + c], x2 = xb[4096 + c];
    float s2 = x0 * x0; s2 = fmaf(x1, x1, s2); s2 = fmaf(x2, x2, s2);
    float dot = ov.x * x0; dot = fmaf(ov.y, x1, dot); dot = fmaf(ov.z, x2, dot);
    float key = fmaf(2.f, dot, -ov.w) - s2;
    unsigned e = fenc(key);
    if (e >= th) {
      int slot = atomicAdd(&cnt[pt], 1);
      if (slot < 16) buf[pt * 16 + slot] = ((u64)e << 32) | (unsigned)(~c);
    }
  }
  __syncthreads();

  if (t < 16) {
    u64 F[10];
    #pragma unroll
    for (int j = 0; j < 10; ++j) F[j] = KSENT;
    int n = cnt[t]; n = (n < 16) ? n : 16;
    for (int e2 = 0; e2 < n; ++e2) ins10k(F, buf[t * 16 + e2]);
    #pragma unroll
    for (int j = 0; j < 10; ++j)
      idxout[(size_t)(b * 2048 + p0 + t) * 10 + j] = keyidx(F[j]);
  }
}

// ---------- knn C=64 partial, MFMA bf16x3, SINGLE-PASS, swapped operands ----------
// 64 query rows x 256 cands/block (8-way split); frag-packed input (K=64).
// r13's gated dual-list push (exact) + r17's snapshot-butterfly on exact u64
// keys across the 4 sub-lanes of each qrow -> final row top-10 in registers;
// lane sub==0 writes pk directly. No LDS merge scratch (1KB ssB only), one
// barrier, no second MFMA pass.
__global__ __launch_bounds__(256)
void k_knn2p(const unsigned short* __restrict__ H, const unsigned short* __restrict__ Lp,
             const float* __restrict__ sq, u64* __restrict__ pk){
  __shared__ float ssB[256];

  const int t  = threadIdx.x;
  const int bx = blockIdx.x;
  const int cc = bx & 7;
  const int rg = (bx >> 3) & 31;
  const int b  = bx >> 8;
  const int p0 = rg * 64;
  const int c0 = cc * 256;
  const int lane = t & 63, w = t >> 6;
  const int la  = (lane & 15) * 8;
  const int sub = lane >> 4;                 // k-chunk of frags == cand sub-block
  const int qrow = w * 16 + (lane & 15);     // this lane's query row (0..63)

  // query fragments (second operand): rows b*2048+p0+w*16..+15, K=64
  const size_t ag = ((size_t)((b * 2048 + p0) >> 4) + w) * 8 + sub;
  bf16x8 aH0 = *(const bf16x8*)&H [ ag      * 128 + la];
  bf16x8 aL0 = *(const bf16x8*)&Lp[ ag      * 128 + la];
  bf16x8 aH1 = *(const bf16x8*)&H [(ag + 4) * 128 + la];
  bf16x8 aL1 = *(const bf16x8*)&Lp[(ag + 4) * 128 + la];

  ssB[t] = sq[b * 2048 + c0 + (t & 255)];
  const float nsA = -sq[b * 2048 + p0 + qrow];

  unsigned S[10], I[10], eth;
  TOPK_INIT(S, I, eth);
  __syncthreads();

  for (int m0 = 0; m0 < 256; m0 += 64) {
    const size_t cgb = ((size_t)((b * 2048 + c0 + m0) >> 4)) * 8 + sub;
    #pragma unroll
    for (int tile = 0; tile < 4; ++tile) {
      const size_t cg = (cgb + (size_t)tile * 8) * 128 + la;
      bf16x8 bH0 = *(const bf16x8*)&H [cg];
      bf16x8 bL0 = *(const bf16x8*)&Lp[cg];
      bf16x8 bH1 = *(const bf16x8*)&H [cg + 512];
      bf16x8 bL1 = *(const bf16x8*)&Lp[cg + 512];
      f32x4 acc = {0.f, 0.f, 0.f, 0.f};
      acc = __builtin_amdgcn_mfma_f32_16x16x32_bf16(bH0, aL0, acc, 0, 0, 0);
      acc = __builtin_amdgcn_mfma_f32_16x16x32_bf16(bL0, aH0, acc, 0, 0, 0);
      acc = __builtin_amdgcn_mfma_f32_16x16x32_bf16(bH0, aH0, acc, 0, 0, 0);
      acc = __builtin_amdgcn_mfma_f32_16x16x32_bf16(bH1, aL1, acc, 0, 0, 0);
      acc = __builtin_amdgcn_mfma_f32_16x16x32_bf16(bL1, aH1, acc, 0, 0, 0);
      acc = __builtin_amdgcn_mfma_f32_16x16x32_bf16(bH1, aH1, acc, 0, 0, 0);
      float4 s4 = *(const float4*)&ssB[m0 + tile * 16 + sub * 4];
      int cbase = c0 + m0 + tile * 16 + sub * 4;
      topk_push32(S, I, eth, fmaf(2.f, acc[0], nsA) - s4.x, cbase);
      topk_push32(S, I, eth, fmaf(2.f, acc[1], nsA) - s4.y, cbase + 1);
      topk_push32(S, I, eth, fmaf(2.f, acc[2], nsA) - s4.z, cbase + 2);
      topk_push32(S, I, eth, fmaf(2.f, acc[3], nsA) - s4.w, cbase + 3);
    }
  }

  // pack exact u64 keys; butterfly-merge the 4 sub-lanes of each qrow
  u64 L[10];
  #pragma unroll
  for (int j = 0; j < 10; ++j)
    L[j] = ((u64)S[j] << 32) | (unsigned)(~I[j]);
  wavemerge10k(L, 16);
  wavemerge10k(L, 32);

  if (sub == 0) {                            // lanes 0-15 of each wave
    size_t base = (size_t)(b * 2048 + p0 + qrow) * 80 + cc * 10;
    #pragma unroll
    for (int j = 0; j < 10; ++j) pk[base + j] = L[j];
  }
}

// ---------- merge 8 partial top-10 key lists -> final idx ----------
__global__ __launch_bounds__(64)
void k_kmerge(const u64* __restrict__ pk, int* __restrict__ idxout){
  int row = blockIdx.x * 64 + threadIdx.x;     // 256 blocks -> 16384
  u64 F[10];
  #pragma unroll
  for (int j = 0; j < 10; ++j) F[j] = KSENT;
  size_t base = (size_t)row * 80;
  for (int e = 0; e < 80; ++e) ins10k(F, pk[base + e]);
  #pragma unroll
  for (int j = 0; j < 10; ++j) idxout[(size_t)row * 10 + j] = keyidx(F[j]);
}

// ---------- UV for stage 1 (C=3): elementwise, reads x [B,3,N] directly ----------
__global__ __launch_bounds__(256)
void k_uv3(const float* __restrict__ x, const float* __restrict__ w1,
           const float* __restrict__ gg, const float* __restrict__ vv,
           float* __restrict__ UV){
  int i = blockIdx.x * 256 + threadIdx.x;      // 4096 blocks
  int p = i >> 6, o = i & 63;
  int b = p >> 11, n = p & 2047;
  float s = gg[o] / sqrtf(vv[o] + BN_EPS);
  const float* xb = x + (size_t)b * 6144 + n;
  float x0 = xb[0], x1 = xb[2048], x2 = xb[4096];
  const float* wr = w1 + o * 6;
  float u = s * (wr[0] * x0 + wr[1] * x1 + wr[2] * x2);
  float v = s * ((wr[3] - wr[0]) * x0 + (wr[4] - wr[1]) * x1 + (wr[5] - wr[2]) * x2);
  UV[(size_t)p * 128 + o] = u;
  UV[(size_t)p * 128 + 64 + o] = v;
}

// ---------- UV for stages 2/3 (C=64): tiled GEMM, s1 folded ----------
__global__ __launch_bounds__(256)
void k_uv(const float* __restrict__ A, int lda, int aoff,
          const float* __restrict__ w,       // [64][128]
          const float* __restrict__ gg, const float* __restrict__ vv,
          float* __restrict__ UV){
  __shared__ float As[16][68];
  __shared__ float Bs[16][68];
  __shared__ float ss[64];
  const int t = threadIdx.x;
  const int tx = t & 15, ty = t >> 4;
  const int m0 = blockIdx.x * 64;
  const int half = blockIdx.y;
  if (t < 64) ss[t] = gg[t] / sqrtf(vv[t] + BN_EPS);
  __syncthreads();
  float acc[4][4] = {};
  for (int k0 = 0; k0 < 64; k0 += 16) {
    for (int i = t; i < 1024; i += 256) {
      int m = i >> 4, k = i & 15;
      As[k][m] = A[(size_t)(m0 + m) * lda + aoff + k0 + k];
    }
    for (int i = t; i < 1024; i += 256) {
      int n = i >> 4, k = i & 15;
      int kk = k0 + k;
      float wv = half ? (w[n * 128 + 64 + kk] - w[n * 128 + kk]) : w[n * 128 + kk];
      Bs[k][n] = wv * ss[n];
    }
    __syncthreads();
    #pragma unroll
    for (int k = 0; k < 16; ++k) {
      float4 a4 = *(const float4*)&As[k][tx * 4];
      float4 b4 = *(const float4*)&Bs[k][ty * 4];
      float am[4] = {a4.x, a4.y, a4.z, a4.w};
      float bm[4] = {b4.x, b4.y, b4.z, b4.w};
      #pragma unroll
      for (int q = 0; q < 4; ++q)
        #pragma unroll
        for (int r = 0; r < 4; ++r)
          acc[q][r] = fmaf(am[q], bm[r], acc[q][r]);
    }
    __syncthreads();
  }
  #pragma unroll
  for (int q = 0; q < 4; ++q)
    #pragma unroll
    for (int r = 0; r < 4; ++r)
      UV[(size_t)(m0 + tx * 4 + q) * 128 + half * 64 + ty * 4 + r] = acc[q][r];
}

// ---------- edge stage with conv2: 8 points/block, grid 2048 ----------
// emits max-pooled output to cat f32, frag-packed bf16 K=64 (kH/kL for knn),
// frag-packed bf16 K=192 (cH/cL for head GEMMs), and |.|^2 (sqout).
__global__ __launch_bounds__(256)
void k_edge2(const float* __restrict__ UV, const int* __restrict__ idx,
             const float* __restrict__ w2,   // [64][64]
             const float* __restrict__ g1, const float* __restrict__ b1,
             const float* __restrict__ m1, const float* __restrict__ v1,
             const float* __restrict__ g2, const float* __restrict__ b2,
             const float* __restrict__ m2, const float* __restrict__ v2,
             float* __restrict__ cat, int coff,
             unsigned short* __restrict__ kH, unsigned short* __restrict__ kL,
             unsigned short* __restrict__ cH, unsigned short* __restrict__ cL,
             float* __restrict__ sqout){
  __shared__ float Ha[64][81];
  __shared__ float Ws[64][68];
  __shared__ float o1s[64], s2s[64], o2s[64];
  __shared__ int   ejs[80];
  const int t = threadIdx.x;
  const int p0 = blockIdx.x * 8;  // 2048 blocks
  const int batch = p0 >> 11;
  if (t < 80) ejs[t] = batch * 2048 + (idx[p0 * 10 + t] & 2047);
  if (t < 64) {
    float s1 = g1[t] / sqrtf(v1[t] + BN_EPS);
    o1s[t] = b1[t] - m1[t] * s1;
    float s2 = g2[t] / sqrtf(v2[t] + BN_EPS);
    s2s[t] = s2;
    o2s[t] = b2[t] - m2[t] * s2;
  }
  for (int i = t; i < 4096; i += 256) {
    int k = i & 63, n = i >> 6;
    Ws[k][n] = w2[n * 64 + k];
  }
  __syncthreads();

  for (int i = t; i < 5120; i += 256) {
    int e = i >> 6, c = i & 63;
    int p = p0 + e / 10;
    float hv = UV[(size_t)ejs[e] * 128 + c] + UV[(size_t)p * 128 + 64 + c] + o1s[c];
    Ha[c][e] = mishf(hv);
  }
  __syncthreads();

  const int tx = t & 15, ty = t >> 4;
  float acc[5][4] = {};
  #pragma unroll 8
  for (int k = 0; k < 64; ++k) {
    float av[5];
    #pragma unroll
    for (int i2 = 0; i2 < 5; ++i2) av[i2] = Ha[k][tx * 5 + i2];
    float4 b4 = *(const float4*)&Ws[k][ty * 4];
    float bv[4] = {b4.x, b4.y, b4.z, b4.w};
    #pragma unroll
    for (int i2 = 0; i2 < 5; ++i2)
      #pragma unroll
      for (int r = 0; r < 4; ++r)
        acc[i2][r] = fmaf(av[i2], bv[r], acc[i2][r]);
  }
  __syncthreads();
  #pragma unroll
  for (int i2 = 0; i2 < 5; ++i2)
    #pragma unroll
    for (int r = 0; r < 4; ++r) {
      int o = ty * 4 + r;
      Ha[o][tx * 5 + i2] = mishf(acc[i2][r] * s2s[o] + o2s[o]);
    }
  __syncthreads();

  for (int i = t; i < 512; i += 256) {
    int p = i >> 6, o = i & 63;
    float mx = Ha[o][p * 10];
    #pragma unroll
    for (int k = 1; k < 10; ++k) mx = fmaxf(mx, Ha[o][p * 10 + k]);
    cat[(size_t)(p0 + p) * 192 + coff + o] = mx;
    unsigned short hh, ll;
    bfsplit(mx, hh, ll);
    int n = p0 + p;
    size_t pos = ((size_t)(n >> 4) * 8 + (o >> 3)) * 128 + (n & 15) * 8 + (o & 7);
    kH[pos] = hh; kL[pos] = ll;
    int kk = coff + o;                       // K=192 packing (head GEMM input)
    size_t pos192 = ((size_t)(n >> 4) * 24 + (kk >> 3)) * 128 + (n & 15) * 8 + (kk & 7);
    cH[pos192] = hh; cL[pos192] = ll;
    // fused |.|^2: wave covers exactly the 64 channels of one point
    float r = mx * mx;
    #pragma unroll
    for (int m = 32; m; m >>= 1) r += __shfl_xor(r, m);
    if (o == 0) sqout[p0 + p] = r;
  }
}

// ---------- edge stage 3 (no conv2): also emits K=192 packed bf16 ----------
__global__ __launch_bounds__(256)
void k_edge3(const float* __restrict__ UV, const int* __restrict__ idx,
             const float* __restrict__ gg, const float* __restrict__ bb,
             const float* __restrict__ mn, const float* __restrict__ vv,
             float* __restrict__ cat,
             unsigned short* __restrict__ cH, unsigned short* __restrict__ cL){
  int i = blockIdx.x * 256 + threadIdx.x;      // 4096 blocks
  int p = i >> 6, o = i & 63;
  int batch = p >> 11;
  float s = gg[o] / sqrtf(vv[o] + BN_EPS);
  float of = bb[o] - mn[o] * s;
  float v_ = UV[(size_t)p * 128 + 64 + o] + of;
  float mx = -INFINITY;
  #pragma unroll
  for (int k = 0; k < 10; ++k) {
    int j = batch * 2048 + (idx[p * 10 + k] & 2047);
    mx = fmaxf(mx, mishf(UV[(size_t)j * 128 + o] + v_));
  }
  cat[(size_t)p * 192 + 128 + o] = mx;
  unsigned short hh, ll;
  bfsplit(mx, hh, ll);
  int kk = 128 + o;
  size_t pos192 = ((size_t)(p >> 4) * 24 + (kk >> 3)) * 128 + (p & 15) * 8 + (kk & 7);
  cH[pos192] = hh; cL[pos192] = ll;
}

// ---------- split src[N][K] -> frag-packed bf16 hi/lo, 8 elems/thread ----------
__global__ __launch_bounds__(256)
void k_split(const float* __restrict__ src, int ld, int koff, int K,
             unsigned short* __restrict__ H, unsigned short* __restrict__ L){
  int i = blockIdx.x * 256 + threadIdx.x;      // one per 8 elements
  int kg = K >> 3;
  int n = i / kg, g = i - n * kg;
  const float* s = &src[(size_t)n * ld + koff + g * 8];
  float4 v0 = *(const float4*)s, v1 = *(const float4*)(s + 4);
  float vv[8] = {v0.x, v0.y, v0.z, v0.w, v1.x, v1.y, v1.z, v1.w};
  u16x8 hh, ll;
  #pragma unroll
  for (int q = 0; q < 8; ++q) {
    unsigned short h_, l_;
    bfsplit(vv[q], h_, l_);
    hh[q] = h_; ll[q] = l_;
  }
  size_t pos = ((size_t)(n >> 4) * kg + g) * 128 + (n & 15) * 8;
  *(u16x8*)&H[pos] = hh;
  *(u16x8*)&L[pos] = ll;
}

// ---------- MFMA bf16x3 head GEMM: 64x64 tile, frags direct from global ----------
#define EP_BNMISH      0
#define EP_MAXGLOB     1
#define EP_BIAS_BNMISH 2

template<int EPI>
__global__ __launch_bounds__(256)
void k_gemm(const unsigned short* __restrict__ APH, const unsigned short* __restrict__ APL,
            const unsigned short* __restrict__ WPH, const unsigned short* __restrict__ WPL,
            int K,
            const float* __restrict__ gg, const float* __restrict__ bb,
            const float* __restrict__ mn, const float* __restrict__ vv,
            const float* __restrict__ bias,
            float* __restrict__ out, int ldo,
            unsigned short* __restrict__ oH, unsigned short* __restrict__ oL, int oldo,
            unsigned* __restrict__ glob)
{
  __shared__ float red[64][17];
  const int t = threadIdx.x;
  const int lane = t & 63, w = t >> 6;
  const int m0 = blockIdx.x * 64, n0 = blockIdx.y * 64;
  const int kg = K >> 3;
  const int la = (lane & 15) * 8;
  f32x4 acc[4] = {{0,0,0,0},{0,0,0,0},{0,0,0,0},{0,0,0,0}};
  const size_t abase = ((size_t)((m0 >> 4) + w) * kg + (lane >> 4)) * 128 + la;

  for (int k0 = 0; k0 < K; k0 += 32) {
    size_t ao = abase + (size_t)(k0 >> 3) * 128;
    bf16x8 aH = *(const bf16x8*)&APH[ao];
    bf16x8 aL = *(const bf16x8*)&APL[ao];
    #pragma unroll
    for (int tt = 0; tt < 4; ++tt) {
      size_t wo = ((size_t)((n0 >> 4) + tt) * kg + (k0 >> 3) + (lane >> 4)) * 128 + la;
      bf16x8 bH = *(const bf16x8*)&WPH[wo];
      bf16x8 bL = *(const bf16x8*)&WPL[wo];
      acc[tt] = __builtin_amdgcn_mfma_f32_16x16x32_bf16(aL, bH, acc[tt], 0, 0, 0);
      acc[tt] = __builtin_amdgcn_mfma_f32_16x16x32_bf16(aH, bL, acc[tt], 0, 0, 0);
      acc[tt] = __builtin_amdgcn_mfma_f32_16x16x32_bf16(aH, bH, acc[tt], 0, 0, 0);
    }
  }

  const int mrow = m0 + w * 16 + ((lane >> 4) << 2);   // C/D: row=(lane>>4)*4+reg
  const int batch = m0 >> 11;

  if (EPI == EP_MAXGLOB) {
    #pragma unroll
    for (int tt = 0; tt < 4; ++tt) {
      int nn = n0 + tt * 16 + (lane & 15);
      float s = gg[nn] / sqrtf(vv[nn] + BN_EPS);
      float f = bb[nn] - mn[nn] * s;
      float mx = -INFINITY;
      #pragma unroll
      for (int r = 0; r < 4; ++r) mx = fmaxf(mx, mishf(acc[tt][r] * s + f));
      red[tt * 16 + (lane & 15)][w * 4 + (lane >> 4)] = mx;
    }
    __syncthreads();
    if (t < 64) {
      float v = red[t][0];
      #pragma unroll
      for (int q = 1; q < 16; ++q) v = fmaxf(v, red[t][q]);
      atomicMax(&glob[batch * 1024 + n0 + t], fenc(v));
    }
  } else {
    #pragma unroll
    for (int tt = 0; tt < 4; ++tt) {
      int nn = n0 + tt * 16 + (lane & 15);
      float s = gg[nn] / sqrtf(vv[nn] + BN_EPS);
      float f = bb[nn] - mn[nn] * s;
      float bv = (EPI == EP_BIAS_BNMISH) ? bias[batch * 512 + nn] : 0.f;
      #pragma unroll
      for (int r = 0; r < 4; ++r) {
        int m = mrow + r;
        float h = mishf((acc[tt][r] + bv) * s + f);
        if (EPI == EP_BIAS_BNMISH) {
          unsigned short hh, ll;
          bfsplit(h, hh, ll);
          size_t pos = ((size_t)(m >> 4) * (oldo >> 3) + (nn >> 3)) * 128
                       + (m & 15) * 8 + (nn & 7);
          oH[pos] = hh; oL[pos] = ll;
        } else {
          out[(size_t)m * ldo + nn] = h;
        }
      }
    }
  }
}

// ---------- t7[b][o] = w7[o, :1024] . glob[b]: one wave per output ----------
__global__ __launch_bounds__(64)
void k_t7(const unsigned* __restrict__ glob, const float* __restrict__ w7,
          float* __restrict__ t7){
  int bo = blockIdx.x;                         // 4096
  int b = bo >> 9, o = bo & 511;
  int j = threadIdx.x;
  const float* wr = w7 + (size_t)o * 1216;
  const unsigned* gr = glob + b * 1024;
  float acc = 0.f;
  #pragma unroll
  for (int c = j; c < 1024; c += 64)
    acc = fmaf(wr[c], fdec(gr[c]), acc);
  #pragma unroll
  for (int m = 32; m; m >>= 1) acc += __shfl_xor(acc, m);
  if (j == 0) t7[bo] = acc;
}

// ---------- final conv ----------
__global__ __launch_bounds__(256)
void k_out(const float* __restrict__ h8, const float* __restrict__ w9,
           float* __restrict__ out)
{
  __shared__ float row[4][256];
  const int t = threadIdx.x;
  const int g = t >> 6, l = t & 63;
  const int p = blockIdx.x * 4 + g;            // 4096 blocks
  for (int c = l; c < 256; c += 64)
    row[g][c] = h8[(size_t)p * 256 + c];
  __syncthreads();
  if (l < 18) {
    float acc = 0.f;
    for (int c = 0; c < 256; ++c)
      acc = fmaf(row[g][c], w9[l * 256 + c], acc);
    int b = p >> 11, n = p & 2047;
    out[(size_t)b * 36864 + l * 2048 + n] = acc;
  }
}

extern "C" void kernel_launch(void* const* d_in, const int* in_sizes, int n_in,
                              void* d_out, int out_size, void* d_ws, size_t ws_size,
                              hipStream_t stream)
{
  const size_t OFF_IDX  = 262144;
  const size_t OFF_CAT  = 917504;
  const size_t OFF_GLOB = 13500416;
  const size_t OFF_T7   = 13533184;
  const size_t OFF_H7   = 13549568;
  const size_t OFF_KNN  = OFF_H7 + 8388608;
  const size_t OFF_PK   = OFF_H7 + 12582912;   // ends 36,618,240 < OFF_H8
  const size_t OFF_H8   = 47104000;
  const size_t NEED     = 63881216;

  static const int EXP[26] = {
    49152, 384, 4096, 8192, 4096, 8192, 196608, 622592, 131072, 4608,
    320, 320, 320, 320, 1024, 1024, 1024, 1024,
    512, 512, 512, 512, 256, 256, 256, 256 };
  if (n_in < 26) { k_diag<<<1,1,0,stream>>>((float*)d_out, 16384.f); return; }
  for (int i = 0; i < 26; ++i)
    if (in_sizes[i] != EXP[i]) {
      k_diag<<<1,1,0,stream>>>((float*)d_out, 4096.f + 128.f * i); return;
    }
  if (out_size != 294912) { k_diag<<<1,1,0,stream>>>((float*)d_out, 20480.f); return; }
  if (ws_size < NEED) {
    k_diag<<<1,1,0,stream>>>((float*)d_out, 24576.f + (float)(ws_size >> 20)); return;
  }

  const float* x  = (const float*)d_in[0];
  const float* w1 = (const float*)d_in[1];
  const float* w2 = (const float*)d_in[2];
  const float* w3 = (const float*)d_in[3];
  const float* w4 = (const float*)d_in[4];
  const float* w5 = (const float*)d_in[5];
  const float* w6 = (const float*)d_in[6];
  const float* w7 = (const float*)d_in[7];
  const float* w8 = (const float*)d_in[8];
  const float* w9 = (const float*)d_in[9];
  const float* g15 = (const float*)d_in[10];
  const float* b15 = (const float*)d_in[11];
  const float* m15 = (const float*)d_in[12];
  const float* v15 = (const float*)d_in[13];
  const float* g6 = (const float*)d_in[14];
  const float* b6 = (const float*)d_in[15];
  const float* m6 = (const float*)d_in[16];
  const float* v6 = (const float*)d_in[17];
  const float* g7 = (const float*)d_in[18];
  const float* b7 = (const float*)d_in[19];
  const float* m7 = (const float*)d_in[20];
  const float* v7 = (const float*)d_in[21];
  const float* g8 = (const float*)d_in[22];
  const float* b8 = (const float*)d_in[23];
  const float* m8 = (const float*)d_in[24];
  const float* v8 = (const float*)d_in[25];

  char* ws = (char*)d_ws;
  float*    sq   = (float*)(ws + 0);                   // 65,536 (stages)
  int*      idx  = (int*)(ws + OFF_IDX);
  float*    cat  = (float*)(ws + OFF_CAT);
  unsigned* glob = (unsigned*)(ws + OFF_GLOB);
  float*    t7   = (float*)(ws + OFF_T7);
  float*    UV   = (float*)(ws + OFF_H7);
  u64*      pk   = (u64*)(ws + OFF_PK);                // 10,485,760 (stages)
  unsigned short* knnH = (unsigned short*)(ws + OFF_KNN);            // 2,097,152
  unsigned short* knnL = (unsigned short*)(ws + OFF_KNN + 2097152);  // 2,097,152
  float*    h8   = (float*)(ws + OFF_H8);              // head (after gemm7)

  // catP lives at OFF_H8 from stage 1 (edge2 writes) through gemm7:
  unsigned short* catH = (unsigned short*)(ws + OFF_H8);             // 6,291,456
  unsigned short* catL = (unsigned short*)(ws + OFF_H8 + 6291456);   // 6,291,456
  // head-phase aliases (lifetimes disjoint):
  unsigned short* h7H  = (unsigned short*)(ws + OFF_H7);             // 16,777,216
  unsigned short* h7L  = (unsigned short*)(ws + OFF_H7 + 16777216);  // 16,777,216
  unsigned short* w6H  = (unsigned short*)(ws + OFF_CAT);            //   393,216
  unsigned short* w6L  = (unsigned short*)(ws + OFF_CAT + 393216);
  unsigned short* w7H  = (unsigned short*)(ws + OFF_CAT + 786432);   //   196,608
  unsigned short* w7L  = (unsigned short*)(ws + OFF_CAT + 983040);
  unsigned short* w8H  = (unsigned short*)(ws + OFF_CAT + 1179648);  //   262,144
  unsigned short* w8L  = (unsigned short*)(ws + OFF_CAT + 1441792);

  k_zero<<<32, 256, 0, stream>>>(glob);        // early; consumed by head phase

  // ---- stage 1 ----
  k_knn3<<<1024, 256, 0, stream>>>(x, idx);
  k_uv3<<<4096, 256, 0, stream>>>(x, w1, g15 + 0, v15 + 0, UV);
  k_edge2<<<2048, 256, 0, stream>>>(UV, idx, w2,
      g15 + 0,  b15 + 0,  m15 + 0,  v15 + 0,
      g15 + 64, b15 + 64, m15 + 64, v15 + 64, cat, 0, knnH, knnL, catH, catL, sq);

  // ---- stage 2 ----
  k_knn2p<<<2048, 256, 0, stream>>>(knnH, knnL, sq, pk);
  k_kmerge<<<256, 64, 0, stream>>>(pk, idx);
  dim3 guv(256, 2);
  k_uv<<<guv, 256, 0, stream>>>(cat, 192, 0, w3, g15 + 128, v15 + 128, UV);
  k_edge2<<<2048, 256, 0, stream>>>(UV, idx, w4,
      g15 + 128, b15 + 128, m15 + 128, v15 + 128,
      g15 + 192, b15 + 192, m15 + 192, v15 + 192, cat, 64, knnH, knnL, catH, catL, sq);

  // ---- stage 3 ----
  k_knn2p<<<2048, 256, 0, stream>>>(knnH, knnL, sq, pk);
  k_kmerge<<<256, 64, 0, stream>>>(pk, idx);
  k_uv<<<guv, 256, 0, stream>>>(cat, 192, 64, w5, g15 + 256, v15 + 256, UV);
  k_edge3<<<4096, 256, 0, stream>>>(UV, idx,
      g15 + 256, b15 + 256, m15 + 256, v15 + 256, cat, catH, catL);

  // ---- weight splits (cat packing fused into edge2/edge3) ----
  k_split<<<96, 256, 0, stream>>>(w6, 192, 0, 192, w6H, w6L);
  k_split<<<48, 256, 0, stream>>>(w7, 1216, 1024, 192, w7H, w7L);
  k_split<<<64, 256, 0, stream>>>(w8, 512, 0, 512, w8H, w8L);

  // ---- head (MFMA bf16x3, no-LDS K-loop) ----
  dim3 g6g(256, 16);
  k_gemm<EP_MAXGLOB><<<g6g, 256, 0, stream>>>(
      catH, catL, w6H, w6L, 192, g6, b6, m6, v6,
      nullptr, nullptr, 0, nullptr, nullptr, 0, glob);
  k_t7<<<4096, 64, 0, stream>>>(glob, w7, t7);
  dim3 g7g(256, 8);
  k_gemm<EP_BIAS_BNMISH><<<g7g, 256, 0, stream>>>(
      catH, catL, w7H, w7L, 192, g7, b7, m7, v7,
      t7, nullptr, 0, h7H, h7L, 512, nullptr);
  dim3 g8g(256, 4);
  k_gemm<EP_BNMISH><<<g8g, 256, 0, stream>>>(
      h7H, h7L, w8H, w8L, 512, g8, b8, m8, v8,
      nullptr, h8, 256, nullptr, nullptr, 0, nullptr);
  k_out<<<4096, 256, 0, stream>>>(h8, w9, (float*)d_out);
}

// Round 23
// 584.977 us; speedup vs baseline: 1.0651x; 1.0651x over previous
//
#include <hip/hip_runtime.h>
#include <math.h>

#define BN_EPS 1e-5f
typedef unsigned long long u64;
typedef __attribute__((ext_vector_type(8))) short bf16x8;
typedef __attribute__((ext_vector_type(8))) unsigned short u16x8;
typedef __attribute__((ext_vector_type(4))) float f32x4;

// mish(x) = x*tanh(ln(1+e^x)) = x*w/(w+2), w = u(u+2), u = e^x (clamped).
__device__ __forceinline__ float mishf(float x){
  float u = __expf(fminf(x, 20.f));
  float w = u * (u + 2.f);
  return x * w / (w + 2.f);
}

__device__ __forceinline__ unsigned fenc(float f){
  unsigned u = __float_as_uint(f);
  return u ^ ((unsigned)((int)u >> 31) | 0x80000000u);
}
__device__ __forceinline__ float fdec(unsigned e){
  unsigned u = (e & 0x80000000u) ? (e & 0x7fffffffu) : ~e;
  return __uint_as_float(u);
}

// bf16x3 split: a = hi + lo (+O(2^-17 a)); rne via bit trick
__device__ __forceinline__ void bfsplit(float a, unsigned short &h, unsigned short &l){
  unsigned u = __float_as_uint(a);
  unsigned hb = (u + 0x7FFFu + ((u >> 16) & 1u)) >> 16;
  h = (unsigned short)hb;
  float hf = __uint_as_float(hb << 16);
  float r = a - hf;
  unsigned v = __float_as_uint(r);
  l = (unsigned short)((v + 0x7FFFu + ((v >> 16) & 1u)) >> 16);
}

// packed key: (value desc, index asc) == lax.top_k order as single u64 compare
__device__ __forceinline__ u64 mkkey(float v, int i){
  return ((u64)fenc(v) << 32) | (unsigned)(~i);
}
__device__ __forceinline__ int keyidx(u64 k){ return (int)(~(unsigned)k); }

__device__ __forceinline__ void ins10k(u64 (&L)[10], u64 k){
  if (k <= L[9]) return;
  #pragma unroll
  for (int p = 9; p >= 1; --p)
    L[p] = (k > L[p-1]) ? L[p-1] : ((k > L[p]) ? k : L[p]);
  L[0] = (k > L[0]) ? k : L[0];
}

// branchless score-only insert into sorted-desc u32 list: 9x v_med3_u32 + max.
// Correct for all rank positions and duplicates (reads-before-writes preserved
// by the p=9..1 order). r22 lesson: the gated DUAL-list (score+index) push is
// wave-divergent and ~3x this cost per streamed cand -- score-only streaming +
// deferred survivor collection (two-pass) is the verified-fastest form.
__device__ __forceinline__ void ins10s(unsigned (&S)[10], unsigned e){
  #pragma unroll
  for (int p = 9; p >= 1; --p){
    unsigned ns;
    asm("v_med3_u32 %0, %1, %2, %3" : "=v"(ns) : "v"(e), "v"(S[p-1]), "v"(S[p]));
    S[p] = ns;
  }
  S[0] = (e > S[0]) ? e : S[0];
}

// snapshot-butterfly merge of sorted-desc lists across lanes differing in bit
// `mask`: snapshot partner's FULL list first (lockstep in-place merge would
// read a partially-merged partner list -> duplicates -> threshold too high).
__device__ __forceinline__ void wavemerge10(unsigned (&S)[10], int mask){
  unsigned T[10];
  #pragma unroll
  for (int j = 0; j < 10; ++j) T[j] = __shfl_xor(S[j], mask);
  #pragma unroll
  for (int j = 0; j < 10; ++j) ins10s(S, T[j]);
}
#define KSENT mkkey(-INFINITY, 0x7fffffff)

__global__ void k_diag(float* __restrict__ out, float v){ out[0] = v; }

__global__ __launch_bounds__(256)
void k_zero(unsigned* __restrict__ p){
  p[blockIdx.x * 256 + threadIdx.x] = 0u;      // 32 blocks -> 8192
}

// ---------- knn C=3 from x [B,3,N]: TWO-PASS, 16 points/block, 16 chunks ----------
// Pass 1: whole batch staged as float4(x,y,z,|x|^2) in LDS (padded stride 129);
// each lane streams 128 cands with a sorted u32 score list (9 med3 + max per
// cand). In-wave snapshot-butterfly merges the 4 chunks per wave; one LDS list
// per wave; t<16 merges 4 wave-lists -> exact 10th-best threshold per point.
// Pass 2: rescan from GLOBAL (bit-identical FMA chains), collect e>=thr
// survivors (<=16) via LDS counter; final 16-thread ins10k gives the exact
// (value desc, idx asc) order. Overlay aliases pts4 -> LDS stays 33KB.
__global__ __launch_bounds__(256)
void k_knn3(const float* __restrict__ x, int* __restrict__ idxout){
  __shared__ __align__(16) char smem[33024];
  float4* pts4   = (float4*)smem;                    // [16][129] (pass 1 only)
  unsigned* m1u  = (unsigned*)smem;                  // [4][10][16] = 2560 B
  unsigned* thr  = (unsigned*)(smem + 2560);         // [16]
  int*      cnt  = (int*)(smem + 2624);              // [16]
  u64*      buf  = (u64*)(smem + 2688);              // [16][16] = 2048 B
  const int t  = threadIdx.x;
  const int b  = blockIdx.x >> 7;                    // 1024 blocks: 128 per batch
  const int p0 = (blockIdx.x & 127) * 16;
  const int pt = t & 15, ch = t >> 4;
  const float* xb = x + (size_t)b * 6144;

  for (int i = t; i < 2048; i += 256) {
    float x0 = xb[i], x1 = xb[2048 + i], x2 = xb[4096 + i];
    float s2 = x0 * x0; s2 = fmaf(x1, x1, s2); s2 = fmaf(x2, x2, s2);
    pts4[(i >> 7) * 129 + (i & 127)] = make_float4(x0, x1, x2, s2);
  }
  __syncthreads();

  const int g = p0 + pt;
  const float4 ov = pts4[(g >> 7) * 129 + (g & 127)];
  unsigned S[10];
  #pragma unroll
  for (int j = 0; j < 10; ++j) S[j] = 0x007FFFFFu;   // fenc(-inf)
  const float4* cp = pts4 + ch * 129;
  #pragma unroll 4
  for (int j = 0; j < 128; ++j) {
    float4 pv = cp[j];
    float dot = ov.x * pv.x; dot = fmaf(ov.y, pv.y, dot); dot = fmaf(ov.z, pv.z, dot);
    float key = fmaf(2.f, dot, -ov.w) - pv.w;
    ins10s(S, fenc(key));
  }
  // merge the 4 chunks resident in this wave (lane bits 4,5 = ch&3)
  wavemerge10(S, 16);
  wavemerge10(S, 32);
  __syncthreads();                                   // pts4 reads done; overlay

  if ((t & 48) == 0) {                               // one lane per (wave, pt)
    int wv = t >> 6;
    #pragma unroll
    for (int j = 0; j < 10; ++j)
      m1u[(wv * 10 + j) * 16 + pt] = S[j];
  }
  __syncthreads();

  if (t < 16) {                                      // final threshold per point
    unsigned F[10];
    #pragma unroll
    for (int j = 0; j < 10; ++j) F[j] = 0x007FFFFFu;
    for (int wv = 0; wv < 4; ++wv)
      #pragma unroll
      for (int j = 0; j < 10; ++j)
        ins10s(F, m1u[(wv * 10 + j) * 16 + t]);
    thr[t] = F[9];
    cnt[t] = 0;
  }
  __syncthreads();

  // pass 2: rescan from global; recompute keys BIT-IDENTICALLY (same chains)
  const unsigned th = thr[pt];
  for (int j = 0; j < 128; ++j) {
    int c = ch * 128 + j;
    float x0 = xb[c], x1 = xb[2048 + c], x2 = xb[4096 + c];
    float s2 = x0 * x0; s2 = fmaf(x1, x1, s2); s2 = fmaf(x2, x2, s2);
    float dot = ov.x * x0; dot = fmaf(ov.y, x1, dot); dot = fmaf(ov.z, x2, dot);
    float key = fmaf(2.f, dot, -ov.w) - s2;
    unsigned e = fenc(key);
    if (e >= th) {
      int slot = atomicAdd(&cnt[pt], 1);
      if (slot < 16) buf[pt * 16 + slot] = ((u64)e << 32) | (unsigned)(~c);
    }
  }
  __syncthreads();

  if (t < 16) {
    u64 F[10];
    #pragma unroll
    for (int j = 0; j < 10; ++j) F[j] = KSENT;
    int n = cnt[t]; n = (n < 16) ? n : 16;
    for (int e2 = 0; e2 < n; ++e2) ins10k(F, buf[t * 16 + e2]);
    #pragma unroll
    for (int j = 0; j < 10; ++j)
      idxout[(size_t)(b * 2048 + p0 + t) * 10 + j] = keyidx(F[j]);
  }
}

// ---------- knn C=64 partial, MFMA bf16x3, TWO-PASS, swapped operands ----------
// 64 query rows x 256 cands/block (8-way split); frag-packed input (K=64).
// Pass 1: MFMA scores, TWO interleaved score lists (S0/S1), exact union-merge,
// then IN-WAVE snapshot-butterfly across the 4 sub-lanes of each qrow ->
// exact per-qrow threshold IN REGISTER.
// Pass 2: recompute the IDENTICAL MFMA chain (bit-identical keys; ssB intact),
// append e>=th survivors (<=16) to per-row LDS buffer; final 64-thread ins10k
// gives exact (value desc, idx asc) order. LDS 9472 B.
// (r22 lesson: single-pass gated dual-list push = wave-divergent insert on
// nearly every cand + u64 butterfly -> 60->77us. Two-pass score-only stands.)
__global__ __launch_bounds__(256)
void k_knn2p(const unsigned short* __restrict__ H, const unsigned short* __restrict__ Lp,
             const float* __restrict__ sq, u64* __restrict__ pk){
  __shared__ __align__(16) char smem[9472];
  float*    ssB = (float*)smem;                  // [256] @0 (both passes)
  int*      cnt = (int*)(smem + 1024);           // [64]
  u64*      buf = (u64*)(smem + 1280);           // [64][16] = 8192 -> 9472

  const int t  = threadIdx.x;
  const int bx = blockIdx.x;
  const int cc = bx & 7;
  const int rg = (bx >> 3) & 31;
  const int b  = bx >> 8;
  const int p0 = rg * 64;
  const int c0 = cc * 256;
  const int lane = t & 63, w = t >> 6;
  const int la  = (lane & 15) * 8;
  const int sub = lane >> 4;                 // k-chunk of frags == cand sub-block
  const int qrow = w * 16 + (lane & 15);     // this lane's query row (0..63)

  // query fragments (second operand): rows b*2048+p0+w*16..+15, K=64
  const size_t ag = ((size_t)((b * 2048 + p0) >> 4) + w) * 8 + sub;
  bf16x8 aH0 = *(const bf16x8*)&H [ ag      * 128 + la];
  bf16x8 aL0 = *(const bf16x8*)&Lp[ ag      * 128 + la];
  bf16x8 aH1 = *(const bf16x8*)&H [(ag + 4) * 128 + la];
  bf16x8 aL1 = *(const bf16x8*)&Lp[(ag + 4) * 128 + la];

  ssB[t] = sq[b * 2048 + c0 + (t & 255)];
  if (t < 64) cnt[t] = 0;
  const float nsA = -sq[b * 2048 + p0 + qrow];

  unsigned S0[10], S1[10];
  #pragma unroll
  for (int j = 0; j < 10; ++j) { S0[j] = 0x007FFFFFu; S1[j] = 0x007FFFFFu; }
  __syncthreads();

  // ---- pass 1: score-only ----
  #pragma unroll 2
  for (int m0 = 0; m0 < 256; m0 += 64) {
    const size_t cgb = ((size_t)((b * 2048 + c0 + m0) >> 4)) * 8 + sub;
    #pragma unroll
    for (int tile = 0; tile < 4; ++tile) {
      const size_t cg = (cgb + (size_t)tile * 8) * 128 + la;
      bf16x8 bH0 = *(const bf16x8*)&H [cg];
      bf16x8 bL0 = *(const bf16x8*)&Lp[cg];
      bf16x8 bH1 = *(const bf16x8*)&H [cg + 512];
      bf16x8 bL1 = *(const bf16x8*)&Lp[cg + 512];
      f32x4 acc = {0.f, 0.f, 0.f, 0.f};
      acc = __builtin_amdgcn_mfma_f32_16x16x32_bf16(bH0, aL0, acc, 0, 0, 0);
      acc = __builtin_amdgcn_mfma_f32_16x16x32_bf16(bL0, aH0, acc, 0, 0, 0);
      acc = __builtin_amdgcn_mfma_f32_16x16x32_bf16(bH0, aH0, acc, 0, 0, 0);
      acc = __builtin_amdgcn_mfma_f32_16x16x32_bf16(bH1, aL1, acc, 0, 0, 0);
      acc = __builtin_amdgcn_mfma_f32_16x16x32_bf16(bL1, aH1, acc, 0, 0, 0);
      acc = __builtin_amdgcn_mfma_f32_16x16x32_bf16(bH1, aH1, acc, 0, 0, 0);
      float4 s4 = *(const float4*)&ssB[m0 + tile * 16 + sub * 4];
      ins10s(S0, fenc(fmaf(2.f, acc[0], nsA) - s4.x));
      ins10s(S1, fenc(fmaf(2.f, acc[1], nsA) - s4.y));
      ins10s(S0, fenc(fmaf(2.f, acc[2], nsA) - s4.z));
      ins10s(S1, fenc(fmaf(2.f, acc[3], nsA) - s4.w));
    }
  }
  #pragma unroll
  for (int j = 0; j < 10; ++j) ins10s(S0, S1[j]);    // exact union top-10

  // in-wave merge across the 4 sub-lanes of each qrow -> threshold in register
  wavemerge10(S0, 16);
  wavemerge10(S0, 32);
  const unsigned thq = S0[9];

  // ---- pass 2: identical MFMA; gated append of survivors ----
  for (int m0 = 0; m0 < 256; m0 += 64) {
    const size_t cgb = ((size_t)((b * 2048 + c0 + m0) >> 4)) * 8 + sub;
    #pragma unroll
    for (int tile = 0; tile < 4; ++tile) {
      const size_t cg = (cgb + (size_t)tile * 8) * 128 + la;
      bf16x8 bH0 = *(const bf16x8*)&H [cg];
      bf16x8 bL0 = *(const bf16x8*)&Lp[cg];
      bf16x8 bH1 = *(const bf16x8*)&H [cg + 512];
      bf16x8 bL1 = *(const bf16x8*)&Lp[cg + 512];
      f32x4 acc = {0.f, 0.f, 0.f, 0.f};
      acc = __builtin_amdgcn_mfma_f32_16x16x32_bf16(bH0, aL0, acc, 0, 0, 0);
      acc = __builtin_amdgcn_mfma_f32_16x16x32_bf16(bL0, aH0, acc, 0, 0, 0);
      acc = __builtin_amdgcn_mfma_f32_16x16x32_bf16(bH0, aH0, acc, 0, 0, 0);
      acc = __builtin_amdgcn_mfma_f32_16x16x32_bf16(bH1, aL1, acc, 0, 0, 0);
      acc = __builtin_amdgcn_mfma_f32_16x16x32_bf16(bL1, aH1, acc, 0, 0, 0);
      acc = __builtin_amdgcn_mfma_f32_16x16x32_bf16(bH1, aH1, acc, 0, 0, 0);
      float4 s4 = *(const float4*)&ssB[m0 + tile * 16 + sub * 4];
      int cbase = c0 + m0 + tile * 16 + sub * 4;
      #pragma unroll
      for (int r = 0; r < 4; ++r) {
        float sr = (r == 0) ? s4.x : (r == 1) ? s4.y : (r == 2) ? s4.z : s4.w;
        unsigned e = fenc(fmaf(2.f, acc[r], nsA) - sr);
        if (e >= thq) {
          int slot = atomicAdd(&cnt[qrow], 1);
          if (slot < 16) buf[qrow * 16 + slot] = ((u64)e << 32) | (unsigned)(~(cbase + r));
        }
      }
    }
  }
  __syncthreads();

  if (t < 64) {
    u64 F[10];
    #pragma unroll
    for (int j = 0; j < 10; ++j) F[j] = KSENT;
    int n = cnt[t]; n = (n < 16) ? n : 16;
    for (int e2 = 0; e2 < n; ++e2) ins10k(F, buf[t * 16 + e2]);
    size_t base = (size_t)(b * 2048 + p0 + t) * 80 + cc * 10;
    #pragma unroll
    for (int j = 0; j < 10; ++j) pk[base + j] = F[j];
  }
}

// ---------- merge 8 partial top-10 key lists -> final idx ----------
__global__ __launch_bounds__(64)
void k_kmerge(const u64* __restrict__ pk, int* __restrict__ idxout){
  int row = blockIdx.x * 64 + threadIdx.x;     // 256 blocks -> 16384
  u64 F[10];
  #pragma unroll
  for (int j = 0; j < 10; ++j) F[j] = KSENT;
  size_t base = (size_t)row * 80;
  for (int e = 0; e < 80; ++e) ins10k(F, pk[base + e]);
  #pragma unroll
  for (int j = 0; j < 10; ++j) idxout[(size_t)row * 10 + j] = keyidx(F[j]);
}

// ---------- UV for stage 1 (C=3): elementwise, reads x [B,3,N] directly ----------
__global__ __launch_bounds__(256)
void k_uv3(const float* __restrict__ x, const float* __restrict__ w1,
           const float* __restrict__ gg, const float* __restrict__ vv,
           float* __restrict__ UV){
  int i = blockIdx.x * 256 + threadIdx.x;      // 4096 blocks
  int p = i >> 6, o = i & 63;
  int b = p >> 11, n = p & 2047;
  float s = gg[o] / sqrtf(vv[o] + BN_EPS);
  const float* xb = x + (size_t)b * 6144 + n;
  float x0 = xb[0], x1 = xb[2048], x2 = xb[4096];
  const float* wr = w1 + o * 6;
  float u = s * (wr[0] * x0 + wr[1] * x1 + wr[2] * x2);
  float v = s * ((wr[3] - wr[0]) * x0 + (wr[4] - wr[1]) * x1 + (wr[5] - wr[2]) * x2);
  UV[(size_t)p * 128 + o] = u;
  UV[(size_t)p * 128 + 64 + o] = v;
}

// ---------- UV for stages 2/3 (C=64): tiled GEMM, s1 folded ----------
__global__ __launch_bounds__(256)
void k_uv(const float* __restrict__ A, int lda, int aoff,
          const float* __restrict__ w,       // [64][128]
          const float* __restrict__ gg, const float* __restrict__ vv,
          float* __restrict__ UV){
  __shared__ float As[16][68];
  __shared__ float Bs[16][68];
  __shared__ float ss[64];
  const int t = threadIdx.x;
  const int tx = t & 15, ty = t >> 4;
  const int m0 = blockIdx.x * 64;
  const int half = blockIdx.y;
  if (t < 64) ss[t] = gg[t] / sqrtf(vv[t] + BN_EPS);
  __syncthreads();
  float acc[4][4] = {};
  for (int k0 = 0; k0 < 64; k0 += 16) {
    for (int i = t; i < 1024; i += 256) {
      int m = i >> 4, k = i & 15;
      As[k][m] = A[(size_t)(m0 + m) * lda + aoff + k0 + k];
    }
    for (int i = t; i < 1024; i += 256) {
      int n = i >> 4, k = i & 15;
      int kk = k0 + k;
      float wv = half ? (w[n * 128 + 64 + kk] - w[n * 128 + kk]) : w[n * 128 + kk];
      Bs[k][n] = wv * ss[n];
    }
    __syncthreads();
    #pragma unroll
    for (int k = 0; k < 16; ++k) {
      float4 a4 = *(const float4*)&As[k][tx * 4];
      float4 b4 = *(const float4*)&Bs[k][ty * 4];
      float am[4] = {a4.x, a4.y, a4.z, a4.w};
      float bm[4] = {b4.x, b4.y, b4.z, b4.w};
      #pragma unroll
      for (int q = 0; q < 4; ++q)
        #pragma unroll
        for (int r = 0; r < 4; ++r)
          acc[q][r] = fmaf(am[q], bm[r], acc[q][r]);
    }
    __syncthreads();
  }
  #pragma unroll
  for (int q = 0; q < 4; ++q)
    #pragma unroll
    for (int r = 0; r < 4; ++r)
      UV[(size_t)(m0 + tx * 4 + q) * 128 + half * 64 + ty * 4 + r] = acc[q][r];
}

// ---------- edge stage with conv2: 8 points/block, grid 2048 ----------
// emits max-pooled output to cat f32, frag-packed bf16 K=64 (kH/kL for knn),
// frag-packed bf16 K=192 (cH/cL for head GEMMs -- replaces k_split(cat)),
// and |.|^2 (sqout). The bfsplit is computed ONCE and reused for both packings.
__global__ __launch_bounds__(256)
void k_edge2(const float* __restrict__ UV, const int* __restrict__ idx,
             const float* __restrict__ w2,   // [64][64]
             const float* __restrict__ g1, const float* __restrict__ b1,
             const float* __restrict__ m1, const float* __restrict__ v1,
             const float* __restrict__ g2, const float* __restrict__ b2,
             const float* __restrict__ m2, const float* __restrict__ v2,
             float* __restrict__ cat, int coff,
             unsigned short* __restrict__ kH, unsigned short* __restrict__ kL,
             unsigned short* __restrict__ cH, unsigned short* __restrict__ cL,
             float* __restrict__ sqout){
  __shared__ float Ha[64][81];
  __shared__ float Ws[64][68];
  __shared__ float o1s[64], s2s[64], o2s[64];
  __shared__ int   ejs[80];
  const int t = threadIdx.x;
  const int p0 = blockIdx.x * 8;  // 2048 blocks
  const int batch = p0 >> 11;
  if (t < 80) ejs[t] = batch * 2048 + (idx[p0 * 10 + t] & 2047);
  if (t < 64) {
    float s1 = g1[t] / sqrtf(v1[t] + BN_EPS);
    o1s[t] = b1[t] - m1[t] * s1;
    float s2 = g2[t] / sqrtf(v2[t] + BN_EPS);
    s2s[t] = s2;
    o2s[t] = b2[t] - m2[t] * s2;
  }
  for (int i = t; i < 4096; i += 256) {
    int k = i & 63, n = i >> 6;
    Ws[k][n] = w2[n * 64 + k];
  }
  __syncthreads();

  for (int i = t; i < 5120; i += 256) {
    int e = i >> 6, c = i & 63;
    int p = p0 + e / 10;
    float hv = UV[(size_t)ejs[e] * 128 + c] + UV[(size_t)p * 128 + 64 + c] + o1s[c];
    Ha[c][e] = mishf(hv);
  }
  __syncthreads();

  const int tx = t & 15, ty = t >> 4;
  float acc[5][4] = {};
  #pragma unroll 8
  for (int k = 0; k < 64; ++k) {
    float av[5];
    #pragma unroll
    for (int i2 = 0; i2 < 5; ++i2) av[i2] = Ha[k][tx * 5 + i2];
    float4 b4 = *(const float4*)&Ws[k][ty * 4];
    float bv[4] = {b4.x, b4.y, b4.z, b4.w};
    #pragma unroll
    for (int i2 = 0; i2 < 5; ++i2)
      #pragma unroll
      for (int r = 0; r < 4; ++r)
        acc[i2][r] = fmaf(av[i2], bv[r], acc[i2][r]);
  }
  __syncthreads();
  #pragma unroll
  for (int i2 = 0; i2 < 5; ++i2)
    #pragma unroll
    for (int r = 0; r < 4; ++r) {
      int o = ty * 4 + r;
      Ha[o][tx * 5 + i2] = mishf(acc[i2][r] * s2s[o] + o2s[o]);
    }
  __syncthreads();

  for (int i = t; i < 512; i += 256) {
    int p = i >> 6, o = i & 63;
    float mx = Ha[o][p * 10];
    #pragma unroll
    for (int k = 1; k < 10; ++k) mx = fmaxf(mx, Ha[o][p * 10 + k]);
    cat[(size_t)(p0 + p) * 192 + coff + o] = mx;
    unsigned short hh, ll;
    bfsplit(mx, hh, ll);
    int n = p0 + p;
    size_t pos = ((size_t)(n >> 4) * 8 + (o >> 3)) * 128 + (n & 15) * 8 + (o & 7);
    kH[pos] = hh; kL[pos] = ll;
    int kk = coff + o;                       // K=192 packing (head GEMM input)
    size_t pos192 = ((size_t)(n >> 4) * 24 + (kk >> 3)) * 128 + (n & 15) * 8 + (kk & 7);
    cH[pos192] = hh; cL[pos192] = ll;
    // fused |.|^2: wave covers exactly the 64 channels of one point
    float r = mx * mx;
    #pragma unroll
    for (int m = 32; m; m >>= 1) r += __shfl_xor(r, m);
    if (o == 0) sqout[p0 + p] = r;
  }
}

// ---------- edge stage 3 (no conv2): also emits K=192 packed bf16 ----------
__global__ __launch_bounds__(256)
void k_edge3(const float* __restrict__ UV, const int* __restrict__ idx,
             const float* __restrict__ gg, const float* __restrict__ bb,
             const float* __restrict__ mn, const float* __restrict__ vv,
             float* __restrict__ cat,
             unsigned short* __restrict__ cH, unsigned short* __restrict__ cL){
  int i = blockIdx.x * 256 + threadIdx.x;      // 4096 blocks
  int p = i >> 6, o = i & 63;
  int batch = p >> 11;
  float s = gg[o] / sqrtf(vv[o] + BN_EPS);
  float of = bb[o] - mn[o] * s;
  float v_ = UV[(size_t)p * 128 + 64 + o] + of;
  float mx = -INFINITY;
  #pragma unroll
  for (int k = 0; k < 10; ++k) {
    int j = batch * 2048 + (idx[p * 10 + k] & 2047);
    mx = fmaxf(mx, mishf(UV[(size_t)j * 128 + o] + v_));
  }
  cat[(size_t)p * 192 + 128 + o] = mx;
  unsigned short hh, ll;
  bfsplit(mx, hh, ll);
  int kk = 128 + o;
  size_t pos192 = ((size_t)(p >> 4) * 24 + (kk >> 3)) * 128 + (p & 15) * 8 + (kk & 7);
  cH[pos192] = hh; cL[pos192] = ll;
}

// ---------- split src[N][K] -> frag-packed bf16 hi/lo, 8 elems/thread ----------
// pos = ((n>>4)*(K/8) + (k>>3))*128 + (n&15)*8 + (k&7); coalesced 16B writes
// (weights only now; cat packing fused into edge2/edge3)
__global__ __launch_bounds__(256)
void k_split(const float* __restrict__ src, int ld, int koff, int K,
             unsigned short* __restrict__ H, unsigned short* __restrict__ L){
  int i = blockIdx.x * 256 + threadIdx.x;      // one per 8 elements
  int kg = K >> 3;
  int n = i / kg, g = i - n * kg;
  const float* s = &src[(size_t)n * ld + koff + g * 8];
  float4 v0 = *(const float4*)s, v1 = *(const float4*)(s + 4);
  float vv[8] = {v0.x, v0.y, v0.z, v0.w, v1.x, v1.y, v1.z, v1.w};
  u16x8 hh, ll;
  #pragma unroll
  for (int q = 0; q < 8; ++q) {
    unsigned short h_, l_;
    bfsplit(vv[q], h_, l_);
    hh[q] = h_; ll[q] = l_;
  }
  size_t pos = ((size_t)(n >> 4) * kg + g) * 128 + (n & 15) * 8;
  *(u16x8*)&H[pos] = hh;
  *(u16x8*)&L[pos] = ll;
}

// ---------- MFMA bf16x3 head GEMM: 64x64 tile, frags direct from global ----------
#define EP_BNMISH      0
#define EP_MAXGLOB     1
#define EP_BIAS_BNMISH 2

template<int EPI>
__global__ __launch_bounds__(256)
void k_gemm(const unsigned short* __restrict__ APH, const unsigned short* __restrict__ APL,
            const unsigned short* __restrict__ WPH, const unsigned short* __restrict__ WPL,
            int K,
            const float* __restrict__ gg, const float* __restrict__ bb,
            const float* __restrict__ mn, const float* __restrict__ vv,
            const float* __restrict__ bias,
            float* __restrict__ out, int ldo,
            unsigned short* __restrict__ oH, unsigned short* __restrict__ oL, int oldo,
            unsigned* __restrict__ glob)
{
  __shared__ float red[64][17];
  const int t = threadIdx.x;
  const int lane = t & 63, w = t >> 6;
  const int m0 = blockIdx.x * 64, n0 = blockIdx.y * 64;
  const int kg = K >> 3;
  const int la = (lane & 15) * 8;
  f32x4 acc[4] = {{0,0,0,0},{0,0,0,0},{0,0,0,0},{0,0,0,0}};
  const size_t abase = ((size_t)((m0 >> 4) + w) * kg + (lane >> 4)) * 128 + la;

  for (int k0 = 0; k0 < K; k0 += 32) {
    size_t ao = abase + (size_t)(k0 >> 3) * 128;
    bf16x8 aH = *(const bf16x8*)&APH[ao];
    bf16x8 aL = *(const bf16x8*)&APL[ao];
    #pragma unroll
    for (int tt = 0; tt < 4; ++tt) {
      size_t wo = ((size_t)((n0 >> 4) + tt) * kg + (k0 >> 3) + (lane >> 4)) * 128 + la;
      bf16x8 bH = *(const bf16x8*)&WPH[wo];
      bf16x8 bL = *(const bf16x8*)&WPL[wo];
      acc[tt] = __builtin_amdgcn_mfma_f32_16x16x32_bf16(aL, bH, acc[tt], 0, 0, 0);
      acc[tt] = __builtin_amdgcn_mfma_f32_16x16x32_bf16(aH, bL, acc[tt], 0, 0, 0);
      acc[tt] = __builtin_amdgcn_mfma_f32_16x16x32_bf16(aH, bH, acc[tt], 0, 0, 0);
    }
  }

  const int mrow = m0 + w * 16 + ((lane >> 4) << 2);   // C/D: row=(lane>>4)*4+reg
  const int batch = m0 >> 11;

  if (EPI == EP_MAXGLOB) {
    #pragma unroll
    for (int tt = 0; tt < 4; ++tt) {
      int nn = n0 + tt * 16 + (lane & 15);
      float s = gg[nn] / sqrtf(vv[nn] + BN_EPS);
      float f = bb[nn] - mn[nn] * s;
      float mx = -INFINITY;
      #pragma unroll
      for (int r = 0; r < 4; ++r) mx = fmaxf(mx, mishf(acc[tt][r] * s + f));
      red[tt * 16 + (lane & 15)][w * 4 + (lane >> 4)] = mx;
    }
    __syncthreads();
    if (t < 64) {
      float v = red[t][0];
      #pragma unroll
      for (int q = 1; q < 16; ++q) v = fmaxf(v, red[t][q]);
      atomicMax(&glob[batch * 1024 + n0 + t], fenc(v));
    }
  } else {
    #pragma unroll
    for (int tt = 0; tt < 4; ++tt) {
      int nn = n0 + tt * 16 + (lane & 15);
      float s = gg[nn] / sqrtf(vv[nn] + BN_EPS);
      float f = bb[nn] - mn[nn] * s;
      float bv = (EPI == EP_BIAS_BNMISH) ? bias[batch * 512 + nn] : 0.f;
      #pragma unroll
      for (int r = 0; r < 4; ++r) {
        int m = mrow + r;
        float h = mishf((acc[tt][r] + bv) * s + f);
        if (EPI == EP_BIAS_BNMISH) {
          unsigned short hh, ll;
          bfsplit(h, hh, ll);
          size_t pos = ((size_t)(m >> 4) * (oldo >> 3) + (nn >> 3)) * 128
                       + (m & 15) * 8 + (nn & 7);
          oH[pos] = hh; oL[pos] = ll;
        } else {
          out[(size_t)m * ldo + nn] = h;
        }
      }
    }
  }
}

// ---------- t7[b][o] = w7[o, :1024] . glob[b]: one wave per output ----------
// grid 4096 (b*512+o), 64 threads; lane j sums c = j, j+64, ... (coalesced),
// then shfl_xor tree reduce. Replaces 16-block serial/uncoalesced version.
__global__ __launch_bounds__(64)
void k_t7(const unsigned* __restrict__ glob, const float* __restrict__ w7,
          float* __restrict__ t7){
  int bo = blockIdx.x;                         // 4096
  int b = bo >> 9, o = bo & 511;
  int j = threadIdx.x;
  const float* wr = w7 + (size_t)o * 1216;
  const unsigned* gr = glob + b * 1024;
  float acc = 0.f;
  #pragma unroll
  for (int c = j; c < 1024; c += 64)
    acc = fmaf(wr[c], fdec(gr[c]), acc);
  #pragma unroll
  for (int m = 32; m; m >>= 1) acc += __shfl_xor(acc, m);
  if (j == 0) t7[bo] = acc;
}

// ---------- final conv ----------
__global__ __launch_bounds__(256)
void k_out(const float* __restrict__ h8, const float* __restrict__ w9,
           float* __restrict__ out)
{
  __shared__ float row[4][256];
  const int t = threadIdx.x;
  const int g = t >> 6, l = t & 63;
  const int p = blockIdx.x * 4 + g;            // 4096 blocks
  for (int c = l; c < 256; c += 64)
    row[g][c] = h8[(size_t)p * 256 + c];
  __syncthreads();
  if (l < 18) {
    float acc = 0.f;
    for (int c = 0; c < 256; ++c)
      acc = fmaf(row[g][c], w9[l * 256 + c], acc);
    int b = p >> 11, n = p & 2047;
    out[(size_t)b * 36864 + l * 2048 + n] = acc;
  }
}

extern "C" void kernel_launch(void* const* d_in, const int* in_sizes, int n_in,
                              void* d_out, int out_size, void* d_ws, size_t ws_size,
                              hipStream_t stream)
{
  // Layout (stage phase): sq@0 (64KB, in the region freed when k_cast died),
  // idx@256K, cat f32@OFF_CAT, glob, t7, UV@OFF_H7 (8.4M), knnP@+8.4M (4M),
  // pk@+12.6M (10.5M, ends 36.6M < OFF_H8), catP@OFF_H8 (12.6M, written by
  // edge2/edge3, live until gemm7). Head: W-splits alias OFF_CAT (cat dead),
  // h7P@OFF_H7 (33.5M, overwrites UV/knnP/pk -- all dead), h8@OFF_H8
  // (overwrites catP after gemm7 consumed it).
  const size_t OFF_IDX  = 262144;
  const size_t OFF_CAT  = 917504;
  const size_t OFF_GLOB = 13500416;
  const size_t OFF_T7   = 13533184;
  const size_t OFF_H7   = 13549568;
  const size_t OFF_KNN  = OFF_H7 + 8388608;
  const size_t OFF_PK   = OFF_H7 + 12582912;   // ends 36,618,240 < OFF_H8
  const size_t OFF_H8   = 47104000;
  const size_t NEED     = 63881216;

  static const int EXP[26] = {
    49152, 384, 4096, 8192, 4096, 8192, 196608, 622592, 131072, 4608,
    320, 320, 320, 320, 1024, 1024, 1024, 1024,
    512, 512, 512, 512, 256, 256, 256, 256 };
  if (n_in < 26) { k_diag<<<1,1,0,stream>>>((float*)d_out, 16384.f); return; }
  for (int i = 0; i < 26; ++i)
    if (in_sizes[i] != EXP[i]) {
      k_diag<<<1,1,0,stream>>>((float*)d_out, 4096.f + 128.f * i); return;
    }
  if (out_size != 294912) { k_diag<<<1,1,0,stream>>>((float*)d_out, 20480.f); return; }
  if (ws_size < NEED) {
    k_diag<<<1,1,0,stream>>>((float*)d_out, 24576.f + (float)(ws_size >> 20)); return;
  }

  const float* x  = (const float*)d_in[0];
  const float* w1 = (const float*)d_in[1];
  const float* w2 = (const float*)d_in[2];
  const float* w3 = (const float*)d_in[3];
  const float* w4 = (const float*)d_in[4];
  const float* w5 = (const float*)d_in[5];
  const float* w6 = (const float*)d_in[6];
  const float* w7 = (const float*)d_in[7];
  const float* w8 = (const float*)d_in[8];
  const float* w9 = (const float*)d_in[9];
  const float* g15 = (const float*)d_in[10];
  const float* b15 = (const float*)d_in[11];
  const float* m15 = (const float*)d_in[12];
  const float* v15 = (const float*)d_in[13];
  const float* g6 = (const float*)d_in[14];
  const float* b6 = (const float*)d_in[15];
  const float* m6 = (const float*)d_in[16];
  const float* v6 = (const float*)d_in[17];
  const float* g7 = (const float*)d_in[18];
  const float* b7 = (const float*)d_in[19];
  const float* m7 = (const float*)d_in[20];
  const float* v7 = (const float*)d_in[21];
  const float* g8 = (const float*)d_in[22];
  const float* b8 = (const float*)d_in[23];
  const float* m8 = (const float*)d_in[24];
  const float* v8 = (const float*)d_in[25];

  char* ws = (char*)d_ws;
  float*    sq   = (float*)(ws + 0);                   // 65,536 (stages)
  int*      idx  = (int*)(ws + OFF_IDX);
  float*    cat  = (float*)(ws + OFF_CAT);
  unsigned* glob = (unsigned*)(ws + OFF_GLOB);
  float*    t7   = (float*)(ws + OFF_T7);
  float*    UV   = (float*)(ws + OFF_H7);
  u64*      pk   = (u64*)(ws + OFF_PK);                // 10,485,760 (stages)
  unsigned short* knnH = (unsigned short*)(ws + OFF_KNN);            // 2,097,152
  unsigned short* knnL = (unsigned short*)(ws + OFF_KNN + 2097152);  // 2,097,152
  float*    h8   = (float*)(ws + OFF_H8);              // head (after gemm7)

  // catP lives at OFF_H8 from stage 1 (edge2 writes) through gemm7:
  unsigned short* catH = (unsigned short*)(ws + OFF_H8);             // 6,291,456
  unsigned short* catL = (unsigned short*)(ws + OFF_H8 + 6291456);   // 6,291,456
  // head-phase aliases (lifetimes disjoint):
  unsigned short* h7H  = (unsigned short*)(ws + OFF_H7);             // 16,777,216
  unsigned short* h7L  = (unsigned short*)(ws + OFF_H7 + 16777216);  // 16,777,216
  unsigned short* w6H  = (unsigned short*)(ws + OFF_CAT);            //   393,216
  unsigned short* w6L  = (unsigned short*)(ws + OFF_CAT + 393216);
  unsigned short* w7H  = (unsigned short*)(ws + OFF_CAT + 786432);   //   196,608
  unsigned short* w7L  = (unsigned short*)(ws + OFF_CAT + 983040);
  unsigned short* w8H  = (unsigned short*)(ws + OFF_CAT + 1179648);  //   262,144
  unsigned short* w8L  = (unsigned short*)(ws + OFF_CAT + 1441792);

  k_zero<<<32, 256, 0, stream>>>(glob);        // early; consumed by head phase

  // ---- stage 1 ----
  k_knn3<<<1024, 256, 0, stream>>>(x, idx);
  k_uv3<<<4096, 256, 0, stream>>>(x, w1, g15 + 0, v15 + 0, UV);
  k_edge2<<<2048, 256, 0, stream>>>(UV, idx, w2,
      g15 + 0,  b15 + 0,  m15 + 0,  v15 + 0,
      g15 + 64, b15 + 64, m15 + 64, v15 + 64, cat, 0, knnH, knnL, catH, catL, sq);

  // ---- stage 2 ----
  k_knn2p<<<2048, 256, 0, stream>>>(knnH, knnL, sq, pk);
  k_kmerge<<<256, 64, 0, stream>>>(pk, idx);
  dim3 guv(256, 2);
  k_uv<<<guv, 256, 0, stream>>>(cat, 192, 0, w3, g15 + 128, v15 + 128, UV);
  k_edge2<<<2048, 256, 0, stream>>>(UV, idx, w4,
      g15 + 128, b15 + 128, m15 + 128, v15 + 128,
      g15 + 192, b15 + 192, m15 + 192, v15 + 192, cat, 64, knnH, knnL, catH, catL, sq);

  // ---- stage 3 ----
  k_knn2p<<<2048, 256, 0, stream>>>(knnH, knnL, sq, pk);
  k_kmerge<<<256, 64, 0, stream>>>(pk, idx);
  k_uv<<<guv, 256, 0, stream>>>(cat, 192, 64, w5, g15 + 256, v15 + 256, UV);
  k_edge3<<<4096, 256, 0, stream>>>(UV, idx,
      g15 + 256, b15 + 256, m15 + 256, v15 + 256, cat, catH, catL);

  // ---- weight splits (cat packing fused into edge2/edge3) ----
  k_split<<<96, 256, 0, stream>>>(w6, 192, 0, 192, w6H, w6L);
  k_split<<<48, 256, 0, stream>>>(w7, 1216, 1024, 192, w7H, w7L);
  k_split<<<64, 256, 0, stream>>>(w8, 512, 0, 512, w8H, w8L);

  // ---- head (MFMA bf16x3, no-LDS K-loop) ----
  dim3 g6g(256, 16);
  k_gemm<EP_MAXGLOB><<<g6g, 256, 0, stream>>>(
      catH, catL, w6H, w6L, 192, g6, b6, m6, v6,
      nullptr, nullptr, 0, nullptr, nullptr, 0, glob);
  k_t7<<<4096, 64, 0, stream>>>(glob, w7, t7);
  dim3 g7g(256, 8);
  k_gemm<EP_BIAS_BNMISH><<<g7g, 256, 0, stream>>>(
      catH, catL, w7H, w7L, 192, g7, b7, m7, v7,
      t7, nullptr, 0, h7H, h7L, 512, nullptr);
  dim3 g8g(256, 4);
  k_gemm<EP_BNMISH><<<g8g, 256, 0, stream>>>(
      h7H, h7L, w8H, w8L, 512, g8, b8, m8, v8,
      nullptr, h8, 256, nullptr, nullptr, 0, nullptr);
  k_out<<<4096, 256, 0, stream>>>(h8, w9, (float*)d_out);
}

// Round 24
// 583.938 us; speedup vs baseline: 1.0670x; 1.0018x over previous
//
#include <hip/hip_runtime.h>
#include <math.h>

#define BN_EPS 1e-5f
typedef unsigned long long u64;
typedef __attribute__((ext_vector_type(8))) short bf16x8;
typedef __attribute__((ext_vector_type(8))) unsigned short u16x8;
typedef __attribute__((ext_vector_type(4))) float f32x4;

// mish(x) = x*tanh(ln(1+e^x)) = x*w/(w+2), w = u(u+2), u = e^x (clamped).
__device__ __forceinline__ float mishf(float x){
  float u = __expf(fminf(x, 20.f));
  float w = u * (u + 2.f);
  return x * w / (w + 2.f);
}

__device__ __forceinline__ unsigned fenc(float f){
  unsigned u = __float_as_uint(f);
  return u ^ ((unsigned)((int)u >> 31) | 0x80000000u);
}
__device__ __forceinline__ float fdec(unsigned e){
  unsigned u = (e & 0x80000000u) ? (e & 0x7fffffffu) : ~e;
  return __uint_as_float(u);
}

// bf16x3 split: a = hi + lo (+O(2^-17 a)); rne via bit trick
__device__ __forceinline__ void bfsplit(float a, unsigned short &h, unsigned short &l){
  unsigned u = __float_as_uint(a);
  unsigned hb = (u + 0x7FFFu + ((u >> 16) & 1u)) >> 16;
  h = (unsigned short)hb;
  float hf = __uint_as_float(hb << 16);
  float r = a - hf;
  unsigned v = __float_as_uint(r);
  l = (unsigned short)((v + 0x7FFFu + ((v >> 16) & 1u)) >> 16);
}

// packed key: (value desc, index asc) == lax.top_k order as single u64 compare
__device__ __forceinline__ u64 mkkey(float v, int i){
  return ((u64)fenc(v) << 32) | (unsigned)(~i);
}
__device__ __forceinline__ int keyidx(u64 k){ return (int)(~(unsigned)k); }

__device__ __forceinline__ void ins10k(u64 (&L)[10], u64 k){
  if (k <= L[9]) return;
  #pragma unroll
  for (int p = 9; p >= 1; --p)
    L[p] = (k > L[p-1]) ? L[p-1] : ((k > L[p]) ? k : L[p]);
  L[0] = (k > L[0]) ? k : L[0];
}

// branchless score-only insert into sorted-desc u32 list: 9x v_med3_u32 + max.
// Correct for all rank positions and duplicates (reads-before-writes preserved
// by the p=9..1 order). r22 lesson: the gated DUAL-list (score+index) push is
// wave-divergent and ~3x this cost per streamed cand -- score-only streaming +
// deferred survivor collection (two-pass) is the verified-fastest form.
__device__ __forceinline__ void ins10s(unsigned (&S)[10], unsigned e){
  #pragma unroll
  for (int p = 9; p >= 1; --p){
    unsigned ns;
    asm("v_med3_u32 %0, %1, %2, %3" : "=v"(ns) : "v"(e), "v"(S[p-1]), "v"(S[p]));
    S[p] = ns;
  }
  S[0] = (e > S[0]) ? e : S[0];
}

// snapshot-butterfly merge of sorted-desc lists across lanes differing in bit
// `mask`: snapshot partner's FULL list first (lockstep in-place merge would
// read a partially-merged partner list -> duplicates -> threshold too high).
__device__ __forceinline__ void wavemerge10(unsigned (&S)[10], int mask){
  unsigned T[10];
  #pragma unroll
  for (int j = 0; j < 10; ++j) T[j] = __shfl_xor(S[j], mask);
  #pragma unroll
  for (int j = 0; j < 10; ++j) ins10s(S, T[j]);
}
#define KSENT mkkey(-INFINITY, 0x7fffffff)

__global__ void k_diag(float* __restrict__ out, float v){ out[0] = v; }

__global__ __launch_bounds__(256)
void k_zero(unsigned* __restrict__ p){
  p[blockIdx.x * 256 + threadIdx.x] = 0u;      // 32 blocks -> 8192
}

// ---------- knn C=3 from x [B,3,N]: TWO-PASS, 16 points/block, 16 chunks ----------
// Pass 1: whole batch staged as float4(x,y,z,|x|^2) in LDS (padded stride 129);
// each lane streams 128 cands with a sorted u32 score list (9 med3 + max per
// cand). In-wave snapshot-butterfly merges the 4 chunks per wave; one LDS list
// per wave; t<16 merges 4 wave-lists -> exact 10th-best threshold per point.
// Pass 2: rescan from GLOBAL (bit-identical FMA chains), collect e>=thr
// survivors (<=16) via LDS counter; final 16-thread ins10k gives the exact
// (value desc, idx asc) order. Overlay aliases pts4 -> LDS stays 33KB.
__global__ __launch_bounds__(256)
void k_knn3(const float* __restrict__ x, int* __restrict__ idxout){
  __shared__ __align__(16) char smem[33024];
  float4* pts4   = (float4*)smem;                    // [16][129] (pass 1 only)
  unsigned* m1u  = (unsigned*)smem;                  // [4][10][16] = 2560 B
  unsigned* thr  = (unsigned*)(smem + 2560);         // [16]
  int*      cnt  = (int*)(smem + 2624);              // [16]
  u64*      buf  = (u64*)(smem + 2688);              // [16][16] = 2048 B
  const int t  = threadIdx.x;
  const int b  = blockIdx.x >> 7;                    // 1024 blocks: 128 per batch
  const int p0 = (blockIdx.x & 127) * 16;
  const int pt = t & 15, ch = t >> 4;
  const float* xb = x + (size_t)b * 6144;

  for (int i = t; i < 2048; i += 256) {
    float x0 = xb[i], x1 = xb[2048 + i], x2 = xb[4096 + i];
    float s2 = x0 * x0; s2 = fmaf(x1, x1, s2); s2 = fmaf(x2, x2, s2);
    pts4[(i >> 7) * 129 + (i & 127)] = make_float4(x0, x1, x2, s2);
  }
  __syncthreads();

  const int g = p0 + pt;
  const float4 ov = pts4[(g >> 7) * 129 + (g & 127)];
  unsigned S[10];
  #pragma unroll
  for (int j = 0; j < 10; ++j) S[j] = 0x007FFFFFu;   // fenc(-inf)
  const float4* cp = pts4 + ch * 129;
  #pragma unroll 4
  for (int j = 0; j < 128; ++j) {
    float4 pv = cp[j];
    float dot = ov.x * pv.x; dot = fmaf(ov.y, pv.y, dot); dot = fmaf(ov.z, pv.z, dot);
    float key = fmaf(2.f, dot, -ov.w) - pv.w;
    ins10s(S, fenc(key));
  }
  // merge the 4 chunks resident in this wave (lane bits 4,5 = ch&3)
  wavemerge10(S, 16);
  wavemerge10(S, 32);
  __syncthreads();                                   // pts4 reads done; overlay

  if ((t & 48) == 0) {                               // one lane per (wave, pt)
    int wv = t >> 6;
    #pragma unroll
    for (int j = 0; j < 10; ++j)
      m1u[(wv * 10 + j) * 16 + pt] = S[j];
  }
  __syncthreads();

  if (t < 16) {                                      // final threshold per point
    unsigned F[10];
    #pragma unroll
    for (int j = 0; j < 10; ++j) F[j] = 0x007FFFFFu;
    for (int wv = 0; wv < 4; ++wv)
      #pragma unroll
      for (int j = 0; j < 10; ++j)
        ins10s(F, m1u[(wv * 10 + j) * 16 + t]);
    thr[t] = F[9];
    cnt[t] = 0;
  }
  __syncthreads();

  // pass 2: rescan from global; recompute keys BIT-IDENTICALLY (same chains)
  const unsigned th = thr[pt];
  for (int j = 0; j < 128; ++j) {
    int c = ch * 128 + j;
    float x0 = xb[c], x1 = xb[2048 + c], x2 = xb[4096 + c];
    float s2 = x0 * x0; s2 = fmaf(x1, x1, s2); s2 = fmaf(x2, x2, s2);
    float dot = ov.x * x0; dot = fmaf(ov.y, x1, dot); dot = fmaf(ov.z, x2, dot);
    float key = fmaf(2.f, dot, -ov.w) - s2;
    unsigned e = fenc(key);
    if (e >= th) {
      int slot = atomicAdd(&cnt[pt], 1);
      if (slot < 16) buf[pt * 16 + slot] = ((u64)e << 32) | (unsigned)(~c);
    }
  }
  __syncthreads();

  if (t < 16) {
    u64 F[10];
    #pragma unroll
    for (int j = 0; j < 10; ++j) F[j] = KSENT;
    int n = cnt[t]; n = (n < 16) ? n : 16;
    for (int e2 = 0; e2 < n; ++e2) ins10k(F, buf[t * 16 + e2]);
    #pragma unroll
    for (int j = 0; j < 10; ++j)
      idxout[(size_t)(b * 2048 + p0 + t) * 10 + j] = keyidx(F[j]);
  }
}

// ---------- knn C=64 partial, MFMA bf16x3, KEY-CACHED TWO-PASS ----------
// 64 query rows x 256 cands/block (8-way split); frag-packed input (K=64).
// Pass 1: MFMA scores with the m0 loop FULLY unrolled; each lane's 64 encoded
// keys are kept in VGPRs (compile-time indices -> registers, no scratch).
// Dual score lists (S0/S1) + union-merge + in-wave butterfly give the exact
// per-qrow threshold in register, as before.
// Pass 2: NO recompute -- iterate the 64 cached keys, gated append of
// survivors (cand index derived from register position). Deletes pass-2's
// 96 MFMAs + 64 fragment loads per lane. VGPR ~36 -> ~115 caps occupancy at
// 4 waves/SIMD = measured occupancy of the old version, so no loss expected.
__global__ __launch_bounds__(256)
void k_knn2p(const unsigned short* __restrict__ H, const unsigned short* __restrict__ Lp,
             const float* __restrict__ sq, u64* __restrict__ pk){
  __shared__ __align__(16) char smem[9472];
  float*    ssB = (float*)smem;                  // [256] @0 (pass 1 only)
  int*      cnt = (int*)(smem + 1024);           // [64]
  u64*      buf = (u64*)(smem + 1280);           // [64][16] = 8192 -> 9472

  const int t  = threadIdx.x;
  const int bx = blockIdx.x;
  const int cc = bx & 7;
  const int rg = (bx >> 3) & 31;
  const int b  = bx >> 8;
  const int p0 = rg * 64;
  const int c0 = cc * 256;
  const int lane = t & 63, w = t >> 6;
  const int la  = (lane & 15) * 8;
  const int sub = lane >> 4;                 // k-chunk of frags == cand sub-block
  const int qrow = w * 16 + (lane & 15);     // this lane's query row (0..63)

  // query fragments (second operand): rows b*2048+p0+w*16..+15, K=64
  const size_t ag = ((size_t)((b * 2048 + p0) >> 4) + w) * 8 + sub;
  bf16x8 aH0 = *(const bf16x8*)&H [ ag      * 128 + la];
  bf16x8 aL0 = *(const bf16x8*)&Lp[ ag      * 128 + la];
  bf16x8 aH1 = *(const bf16x8*)&H [(ag + 4) * 128 + la];
  bf16x8 aL1 = *(const bf16x8*)&Lp[(ag + 4) * 128 + la];

  ssB[t] = sq[b * 2048 + c0 + (t & 255)];
  if (t < 64) cnt[t] = 0;
  const float nsA = -sq[b * 2048 + p0 + qrow];

  unsigned S0[10], S1[10];
  unsigned keys[64];
  #pragma unroll
  for (int j = 0; j < 10; ++j) { S0[j] = 0x007FFFFFu; S1[j] = 0x007FFFFFu; }
  __syncthreads();

  // ---- pass 1: score + key-cache (fully unrolled -> keys[] in registers) ----
  #pragma unroll
  for (int m0i = 0; m0i < 4; ++m0i) {
    const size_t cgb = ((size_t)((b * 2048 + c0 + m0i * 64) >> 4)) * 8 + sub;
    #pragma unroll
    for (int tile = 0; tile < 4; ++tile) {
      const size_t cg = (cgb + (size_t)tile * 8) * 128 + la;
      bf16x8 bH0 = *(const bf16x8*)&H [cg];
      bf16x8 bL0 = *(const bf16x8*)&Lp[cg];
      bf16x8 bH1 = *(const bf16x8*)&H [cg + 512];
      bf16x8 bL1 = *(const bf16x8*)&Lp[cg + 512];
      f32x4 acc = {0.f, 0.f, 0.f, 0.f};
      acc = __builtin_amdgcn_mfma_f32_16x16x32_bf16(bH0, aL0, acc, 0, 0, 0);
      acc = __builtin_amdgcn_mfma_f32_16x16x32_bf16(bL0, aH0, acc, 0, 0, 0);
      acc = __builtin_amdgcn_mfma_f32_16x16x32_bf16(bH0, aH0, acc, 0, 0, 0);
      acc = __builtin_amdgcn_mfma_f32_16x16x32_bf16(bH1, aL1, acc, 0, 0, 0);
      acc = __builtin_amdgcn_mfma_f32_16x16x32_bf16(bL1, aH1, acc, 0, 0, 0);
      acc = __builtin_amdgcn_mfma_f32_16x16x32_bf16(bH1, aH1, acc, 0, 0, 0);
      float4 s4 = *(const float4*)&ssB[m0i * 64 + tile * 16 + sub * 4];
      unsigned e0 = fenc(fmaf(2.f, acc[0], nsA) - s4.x);
      unsigned e1 = fenc(fmaf(2.f, acc[1], nsA) - s4.y);
      unsigned e2 = fenc(fmaf(2.f, acc[2], nsA) - s4.z);
      unsigned e3 = fenc(fmaf(2.f, acc[3], nsA) - s4.w);
      keys[m0i * 16 + tile * 4 + 0] = e0;
      keys[m0i * 16 + tile * 4 + 1] = e1;
      keys[m0i * 16 + tile * 4 + 2] = e2;
      keys[m0i * 16 + tile * 4 + 3] = e3;
      ins10s(S0, e0);
      ins10s(S1, e1);
      ins10s(S0, e2);
      ins10s(S1, e3);
    }
  }
  #pragma unroll
  for (int j = 0; j < 10; ++j) ins10s(S0, S1[j]);    // exact union top-10

  // in-wave merge across the 4 sub-lanes of each qrow -> threshold in register
  wavemerge10(S0, 16);
  wavemerge10(S0, 32);
  const unsigned thq = S0[9];

  // ---- pass 2: cached keys, gated append of survivors (no recompute) ----
  #pragma unroll
  for (int q = 0; q < 64; ++q) {
    unsigned e = keys[q];
    if (e >= thq) {
      int cand = c0 + (q >> 4) * 64 + ((q >> 2) & 3) * 16 + sub * 4 + (q & 3);
      int slot = atomicAdd(&cnt[qrow], 1);
      if (slot < 16) buf[qrow * 16 + slot] = ((u64)e << 32) | (unsigned)(~cand);
    }
  }
  __syncthreads();

  if (t < 64) {
    u64 F[10];
    #pragma unroll
    for (int j = 0; j < 10; ++j) F[j] = KSENT;
    int n = cnt[t]; n = (n < 16) ? n : 16;
    for (int e2 = 0; e2 < n; ++e2) ins10k(F, buf[t * 16 + e2]);
    size_t base = (size_t)(b * 2048 + p0 + t) * 80 + cc * 10;
    #pragma unroll
    for (int j = 0; j < 10; ++j) pk[base + j] = F[j];
  }
}

// ---------- merge 8 partial top-10 key lists -> final idx ----------
__global__ __launch_bounds__(64)
void k_kmerge(const u64* __restrict__ pk, int* __restrict__ idxout){
  int row = blockIdx.x * 64 + threadIdx.x;     // 256 blocks -> 16384
  u64 F[10];
  #pragma unroll
  for (int j = 0; j < 10; ++j) F[j] = KSENT;
  size_t base = (size_t)row * 80;
  for (int e = 0; e < 80; ++e) ins10k(F, pk[base + e]);
  #pragma unroll
  for (int j = 0; j < 10; ++j) idxout[(size_t)row * 10 + j] = keyidx(F[j]);
}

// ---------- UV for stage 1 (C=3): elementwise, reads x [B,3,N] directly ----------
__global__ __launch_bounds__(256)
void k_uv3(const float* __restrict__ x, const float* __restrict__ w1,
           const float* __restrict__ gg, const float* __restrict__ vv,
           float* __restrict__ UV){
  int i = blockIdx.x * 256 + threadIdx.x;      // 4096 blocks
  int p = i >> 6, o = i & 63;
  int b = p >> 11, n = p & 2047;
  float s = gg[o] / sqrtf(vv[o] + BN_EPS);
  const float* xb = x + (size_t)b * 6144 + n;
  float x0 = xb[0], x1 = xb[2048], x2 = xb[4096];
  const float* wr = w1 + o * 6;
  float u = s * (wr[0] * x0 + wr[1] * x1 + wr[2] * x2);
  float v = s * ((wr[3] - wr[0]) * x0 + (wr[4] - wr[1]) * x1 + (wr[5] - wr[2]) * x2);
  UV[(size_t)p * 128 + o] = u;
  UV[(size_t)p * 128 + 64 + o] = v;
}

// ---------- UV for stages 2/3 (C=64): tiled GEMM, s1 folded ----------
__global__ __launch_bounds__(256)
void k_uv(const float* __restrict__ A, int lda, int aoff,
          const float* __restrict__ w,       // [64][128]
          const float* __restrict__ gg, const float* __restrict__ vv,
          float* __restrict__ UV){
  __shared__ float As[16][68];
  __shared__ float Bs[16][68];
  __shared__ float ss[64];
  const int t = threadIdx.x;
  const int tx = t & 15, ty = t >> 4;
  const int m0 = blockIdx.x * 64;
  const int half = blockIdx.y;
  if (t < 64) ss[t] = gg[t] / sqrtf(vv[t] + BN_EPS);
  __syncthreads();
  float acc[4][4] = {};
  for (int k0 = 0; k0 < 64; k0 += 16) {
    for (int i = t; i < 1024; i += 256) {
      int m = i >> 4, k = i & 15;
      As[k][m] = A[(size_t)(m0 + m) * lda + aoff + k0 + k];
    }
    for (int i = t; i < 1024; i += 256) {
      int n = i >> 4, k = i & 15;
      int kk = k0 + k;
      float wv = half ? (w[n * 128 + 64 + kk] - w[n * 128 + kk]) : w[n * 128 + kk];
      Bs[k][n] = wv * ss[n];
    }
    __syncthreads();
    #pragma unroll
    for (int k = 0; k < 16; ++k) {
      float4 a4 = *(const float4*)&As[k][tx * 4];
      float4 b4 = *(const float4*)&Bs[k][ty * 4];
      float am[4] = {a4.x, a4.y, a4.z, a4.w};
      float bm[4] = {b4.x, b4.y, b4.z, b4.w};
      #pragma unroll
      for (int q = 0; q < 4; ++q)
        #pragma unroll
        for (int r = 0; r < 4; ++r)
          acc[q][r] = fmaf(am[q], bm[r], acc[q][r]);
    }
    __syncthreads();
  }
  #pragma unroll
  for (int q = 0; q < 4; ++q)
    #pragma unroll
    for (int r = 0; r < 4; ++r)
      UV[(size_t)(m0 + tx * 4 + q) * 128 + half * 64 + ty * 4 + r] = acc[q][r];
}

// ---------- edge stage with conv2: 8 points/block, grid 2048 ----------
// emits max-pooled output to cat f32, frag-packed bf16 K=64 (kH/kL for knn),
// frag-packed bf16 K=192 (cH/cL for head GEMMs -- replaces k_split(cat)),
// and |.|^2 (sqout). The bfsplit is computed ONCE and reused for both packings.
__global__ __launch_bounds__(256)
void k_edge2(const float* __restrict__ UV, const int* __restrict__ idx,
             const float* __restrict__ w2,   // [64][64]
             const float* __restrict__ g1, const float* __restrict__ b1,
             const float* __restrict__ m1, const float* __restrict__ v1,
             const float* __restrict__ g2, const float* __restrict__ b2,
             const float* __restrict__ m2, const float* __restrict__ v2,
             float* __restrict__ cat, int coff,
             unsigned short* __restrict__ kH, unsigned short* __restrict__ kL,
             unsigned short* __restrict__ cH, unsigned short* __restrict__ cL,
             float* __restrict__ sqout){
  __shared__ float Ha[64][81];
  __shared__ float Ws[64][68];
  __shared__ float o1s[64], s2s[64], o2s[64];
  __shared__ int   ejs[80];
  const int t = threadIdx.x;
  const int p0 = blockIdx.x * 8;  // 2048 blocks
  const int batch = p0 >> 11;
  if (t < 80) ejs[t] = batch * 2048 + (idx[p0 * 10 + t] & 2047);
  if (t < 64) {
    float s1 = g1[t] / sqrtf(v1[t] + BN_EPS);
    o1s[t] = b1[t] - m1[t] * s1;
    float s2 = g2[t] / sqrtf(v2[t] + BN_EPS);
    s2s[t] = s2;
    o2s[t] = b2[t] - m2[t] * s2;
  }
  for (int i = t; i < 4096; i += 256) {
    int k = i & 63, n = i >> 6;
    Ws[k][n] = w2[n * 64 + k];
  }
  __syncthreads();

  for (int i = t; i < 5120; i += 256) {
    int e = i >> 6, c = i & 63;
    int p = p0 + e / 10;
    float hv = UV[(size_t)ejs[e] * 128 + c] + UV[(size_t)p * 128 + 64 + c] + o1s[c];
    Ha[c][e] = mishf(hv);
  }
  __syncthreads();

  const int tx = t & 15, ty = t >> 4;
  float acc[5][4] = {};
  #pragma unroll 8
  for (int k = 0; k < 64; ++k) {
    float av[5];
    #pragma unroll
    for (int i2 = 0; i2 < 5; ++i2) av[i2] = Ha[k][tx * 5 + i2];
    float4 b4 = *(const float4*)&Ws[k][ty * 4];
    float bv[4] = {b4.x, b4.y, b4.z, b4.w};
    #pragma unroll
    for (int i2 = 0; i2 < 5; ++i2)
      #pragma unroll
      for (int r = 0; r < 4; ++r)
        acc[i2][r] = fmaf(av[i2], bv[r], acc[i2][r]);
  }
  __syncthreads();
  #pragma unroll
  for (int i2 = 0; i2 < 5; ++i2)
    #pragma unroll
    for (int r = 0; r < 4; ++r) {
      int o = ty * 4 + r;
      Ha[o][tx * 5 + i2] = mishf(acc[i2][r] * s2s[o] + o2s[o]);
    }
  __syncthreads();

  for (int i = t; i < 512; i += 256) {
    int p = i >> 6, o = i & 63;
    float mx = Ha[o][p * 10];
    #pragma unroll
    for (int k = 1; k < 10; ++k) mx = fmaxf(mx, Ha[o][p * 10 + k]);
    cat[(size_t)(p0 + p) * 192 + coff + o] = mx;
    unsigned short hh, ll;
    bfsplit(mx, hh, ll);
    int n = p0 + p;
    size_t pos = ((size_t)(n >> 4) * 8 + (o >> 3)) * 128 + (n & 15) * 8 + (o & 7);
    kH[pos] = hh; kL[pos] = ll;
    int kk = coff + o;                       // K=192 packing (head GEMM input)
    size_t pos192 = ((size_t)(n >> 4) * 24 + (kk >> 3)) * 128 + (n & 15) * 8 + (kk & 7);
    cH[pos192] = hh; cL[pos192] = ll;
    // fused |.|^2: wave covers exactly the 64 channels of one point
    float r = mx * mx;
    #pragma unroll
    for (int m = 32; m; m >>= 1) r += __shfl_xor(r, m);
    if (o == 0) sqout[p0 + p] = r;
  }
}

// ---------- edge stage 3 (no conv2): also emits K=192 packed bf16 ----------
__global__ __launch_bounds__(256)
void k_edge3(const float* __restrict__ UV, const int* __restrict__ idx,
             const float* __restrict__ gg, const float* __restrict__ bb,
             const float* __restrict__ mn, const float* __restrict__ vv,
             float* __restrict__ cat,
             unsigned short* __restrict__ cH, unsigned short* __restrict__ cL){
  int i = blockIdx.x * 256 + threadIdx.x;      // 4096 blocks
  int p = i >> 6, o = i & 63;
  int batch = p >> 11;
  float s = gg[o] / sqrtf(vv[o] + BN_EPS);
  float of = bb[o] - mn[o] * s;
  float v_ = UV[(size_t)p * 128 + 64 + o] + of;
  float mx = -INFINITY;
  #pragma unroll
  for (int k = 0; k < 10; ++k) {
    int j = batch * 2048 + (idx[p * 10 + k] & 2047);
    mx = fmaxf(mx, mishf(UV[(size_t)j * 128 + o] + v_));
  }
  cat[(size_t)p * 192 + 128 + o] = mx;
  unsigned short hh, ll;
  bfsplit(mx, hh, ll);
  int kk = 128 + o;
  size_t pos192 = ((size_t)(p >> 4) * 24 + (kk >> 3)) * 128 + (p & 15) * 8 + (kk & 7);
  cH[pos192] = hh; cL[pos192] = ll;
}

// ---------- split src[N][K] -> frag-packed bf16 hi/lo, 8 elems/thread ----------
// pos = ((n>>4)*(K/8) + (k>>3))*128 + (n&15)*8 + (k&7); coalesced 16B writes
// (weights only now; cat packing fused into edge2/edge3)
__global__ __launch_bounds__(256)
void k_split(const float* __restrict__ src, int ld, int koff, int K,
             unsigned short* __restrict__ H, unsigned short* __restrict__ L){
  int i = blockIdx.x * 256 + threadIdx.x;      // one per 8 elements
  int kg = K >> 3;
  int n = i / kg, g = i - n * kg;
  const float* s = &src[(size_t)n * ld + koff + g * 8];
  float4 v0 = *(const float4*)s, v1 = *(const float4*)(s + 4);
  float vv[8] = {v0.x, v0.y, v0.z, v0.w, v1.x, v1.y, v1.z, v1.w};
  u16x8 hh, ll;
  #pragma unroll
  for (int q = 0; q < 8; ++q) {
    unsigned short h_, l_;
    bfsplit(vv[q], h_, l_);
    hh[q] = h_; ll[q] = l_;
  }
  size_t pos = ((size_t)(n >> 4) * kg + g) * 128 + (n & 15) * 8;
  *(u16x8*)&H[pos] = hh;
  *(u16x8*)&L[pos] = ll;
}

// ---------- MFMA bf16x3 head GEMM: 64x64 tile, frags direct from global ----------
#define EP_BNMISH      0
#define EP_MAXGLOB     1
#define EP_BIAS_BNMISH 2

template<int EPI>
__global__ __launch_bounds__(256)
void k_gemm(const unsigned short* __restrict__ APH, const unsigned short* __restrict__ APL,
            const unsigned short* __restrict__ WPH, const unsigned short* __restrict__ WPL,
            int K,
            const float* __restrict__ gg, const float* __restrict__ bb,
            const float* __restrict__ mn, const float* __restrict__ vv,
            const float* __restrict__ bias,
            float* __restrict__ out, int ldo,
            unsigned short* __restrict__ oH, unsigned short* __restrict__ oL, int oldo,
            unsigned* __restrict__ glob)
{
  __shared__ float red[64][17];
  const int t = threadIdx.x;
  const int lane = t & 63, w = t >> 6;
  const int m0 = blockIdx.x * 64, n0 = blockIdx.y * 64;
  const int kg = K >> 3;
  const int la = (lane & 15) * 8;
  f32x4 acc[4] = {{0,0,0,0},{0,0,0,0},{0,0,0,0},{0,0,0,0}};
  const size_t abase = ((size_t)((m0 >> 4) + w) * kg + (lane >> 4)) * 128 + la;

  for (int k0 = 0; k0 < K; k0 += 32) {
    size_t ao = abase + (size_t)(k0 >> 3) * 128;
    bf16x8 aH = *(const bf16x8*)&APH[ao];
    bf16x8 aL = *(const bf16x8*)&APL[ao];
    #pragma unroll
    for (int tt = 0; tt < 4; ++tt) {
      size_t wo = ((size_t)((n0 >> 4) + tt) * kg + (k0 >> 3) + (lane >> 4)) * 128 + la;
      bf16x8 bH = *(const bf16x8*)&WPH[wo];
      bf16x8 bL = *(const bf16x8*)&WPL[wo];
      acc[tt] = __builtin_amdgcn_mfma_f32_16x16x32_bf16(aL, bH, acc[tt], 0, 0, 0);
      acc[tt] = __builtin_amdgcn_mfma_f32_16x16x32_bf16(aH, bL, acc[tt], 0, 0, 0);
      acc[tt] = __builtin_amdgcn_mfma_f32_16x16x32_bf16(aH, bH, acc[tt], 0, 0, 0);
    }
  }

  const int mrow = m0 + w * 16 + ((lane >> 4) << 2);   // C/D: row=(lane>>4)*4+reg
  const int batch = m0 >> 11;

  if (EPI == EP_MAXGLOB) {
    #pragma unroll
    for (int tt = 0; tt < 4; ++tt) {
      int nn = n0 + tt * 16 + (lane & 15);
      float s = gg[nn] / sqrtf(vv[nn] + BN_EPS);
      float f = bb[nn] - mn[nn] * s;
      float mx = -INFINITY;
      #pragma unroll
      for (int r = 0; r < 4; ++r) mx = fmaxf(mx, mishf(acc[tt][r] * s + f));
      red[tt * 16 + (lane & 15)][w * 4 + (lane >> 4)] = mx;
    }
    __syncthreads();
    if (t < 64) {
      float v = red[t][0];
      #pragma unroll
      for (int q = 1; q < 16; ++q) v = fmaxf(v, red[t][q]);
      atomicMax(&glob[batch * 1024 + n0 + t], fenc(v));
    }
  } else {
    #pragma unroll
    for (int tt = 0; tt < 4; ++tt) {
      int nn = n0 + tt * 16 + (lane & 15);
      float s = gg[nn] / sqrtf(vv[nn] + BN_EPS);
      float f = bb[nn] - mn[nn] * s;
      float bv = (EPI == EP_BIAS_BNMISH) ? bias[batch * 512 + nn] : 0.f;
      #pragma unroll
      for (int r = 0; r < 4; ++r) {
        int m = mrow + r;
        float h = mishf((acc[tt][r] + bv) * s + f);
        if (EPI == EP_BIAS_BNMISH) {
          unsigned short hh, ll;
          bfsplit(h, hh, ll);
          size_t pos = ((size_t)(m >> 4) * (oldo >> 3) + (nn >> 3)) * 128
                       + (m & 15) * 8 + (nn & 7);
          oH[pos] = hh; oL[pos] = ll;
        } else {
          out[(size_t)m * ldo + nn] = h;
        }
      }
    }
  }
}

// ---------- t7[b][o] = w7[o, :1024] . glob[b]: one wave per output ----------
// grid 4096 (b*512+o), 64 threads; lane j sums c = j, j+64, ... (coalesced),
// then shfl_xor tree reduce. Replaces 16-block serial/uncoalesced version.
__global__ __launch_bounds__(64)
void k_t7(const unsigned* __restrict__ glob, const float* __restrict__ w7,
          float* __restrict__ t7){
  int bo = blockIdx.x;                         // 4096
  int b = bo >> 9, o = bo & 511;
  int j = threadIdx.x;
  const float* wr = w7 + (size_t)o * 1216;
  const unsigned* gr = glob + b * 1024;
  float acc = 0.f;
  #pragma unroll
  for (int c = j; c < 1024; c += 64)
    acc = fmaf(wr[c], fdec(gr[c]), acc);
  #pragma unroll
  for (int m = 32; m; m >>= 1) acc += __shfl_xor(acc, m);
  if (j == 0) t7[bo] = acc;
}

// ---------- final conv ----------
__global__ __launch_bounds__(256)
void k_out(const float* __restrict__ h8, const float* __restrict__ w9,
           float* __restrict__ out)
{
  __shared__ float row[4][256];
  const int t = threadIdx.x;
  const int g = t >> 6, l = t & 63;
  const int p = blockIdx.x * 4 + g;            // 4096 blocks
  for (int c = l; c < 256; c += 64)
    row[g][c] = h8[(size_t)p * 256 + c];
  __syncthreads();
  if (l < 18) {
    float acc = 0.f;
    for (int c = 0; c < 256; ++c)
      acc = fmaf(row[g][c], w9[l * 256 + c], acc);
    int b = p >> 11, n = p & 2047;
    out[(size_t)b * 36864 + l * 2048 + n] = acc;
  }
}

extern "C" void kernel_launch(void* const* d_in, const int* in_sizes, int n_in,
                              void* d_out, int out_size, void* d_ws, size_t ws_size,
                              hipStream_t stream)
{
  // Layout (stage phase): sq@0 (64KB, in the region freed when k_cast died),
  // idx@256K, cat f32@OFF_CAT, glob, t7, UV@OFF_H7 (8.4M), knnP@+8.4M (4M),
  // pk@+12.6M (10.5M, ends 36.6M < OFF_H8), catP@OFF_H8 (12.6M, written by
  // edge2/edge3, live until gemm7). Head: W-splits alias OFF_CAT (cat dead),
  // h7P@OFF_H7 (33.5M, overwrites UV/knnP/pk -- all dead), h8@OFF_H8
  // (overwrites catP after gemm7 consumed it).
  const size_t OFF_IDX  = 262144;
  const size_t OFF_CAT  = 917504;
  const size_t OFF_GLOB = 13500416;
  const size_t OFF_T7   = 13533184;
  const size_t OFF_H7   = 13549568;
  const size_t OFF_KNN  = OFF_H7 + 8388608;
  const size_t OFF_PK   = OFF_H7 + 12582912;   // ends 36,618,240 < OFF_H8
  const size_t OFF_H8   = 47104000;
  const size_t NEED     = 63881216;

  static const int EXP[26] = {
    49152, 384, 4096, 8192, 4096, 8192, 196608, 622592, 131072, 4608,
    320, 320, 320, 320, 1024, 1024, 1024, 1024,
    512, 512, 512, 512, 256, 256, 256, 256 };
  if (n_in < 26) { k_diag<<<1,1,0,stream>>>((float*)d_out, 16384.f); return; }
  for (int i = 0; i < 26; ++i)
    if (in_sizes[i] != EXP[i]) {
      k_diag<<<1,1,0,stream>>>((float*)d_out, 4096.f + 128.f * i); return;
    }
  if (out_size != 294912) { k_diag<<<1,1,0,stream>>>((float*)d_out, 20480.f); return; }
  if (ws_size < NEED) {
    k_diag<<<1,1,0,stream>>>((float*)d_out, 24576.f + (float)(ws_size >> 20)); return;
  }

  const float* x  = (const float*)d_in[0];
  const float* w1 = (const float*)d_in[1];
  const float* w2 = (const float*)d_in[2];
  const float* w3 = (const float*)d_in[3];
  const float* w4 = (const float*)d_in[4];
  const float* w5 = (const float*)d_in[5];
  const float* w6 = (const float*)d_in[6];
  const float* w7 = (const float*)d_in[7];
  const float* w8 = (const float*)d_in[8];
  const float* w9 = (const float*)d_in[9];
  const float* g15 = (const float*)d_in[10];
  const float* b15 = (const float*)d_in[11];
  const float* m15 = (const float*)d_in[12];
  const float* v15 = (const float*)d_in[13];
  const float* g6 = (const float*)d_in[14];
  const float* b6 = (const float*)d_in[15];
  const float* m6 = (const float*)d_in[16];
  const float* v6 = (const float*)d_in[17];
  const float* g7 = (const float*)d_in[18];
  const float* b7 = (const float*)d_in[19];
  const float* m7 = (const float*)d_in[20];
  const float* v7 = (const float*)d_in[21];
  const float* g8 = (const float*)d_in[22];
  const float* b8 = (const float*)d_in[23];
  const float* m8 = (const float*)d_in[24];
  const float* v8 = (const float*)d_in[25];

  char* ws = (char*)d_ws;
  float*    sq   = (float*)(ws + 0);                   // 65,536 (stages)
  int*      idx  = (int*)(ws + OFF_IDX);
  float*    cat  = (float*)(ws + OFF_CAT);
  unsigned* glob = (unsigned*)(ws + OFF_GLOB);
  float*    t7   = (float*)(ws + OFF_T7);
  float*    UV   = (float*)(ws + OFF_H7);
  u64*      pk   = (u64*)(ws + OFF_PK);                // 10,485,760 (stages)
  unsigned short* knnH = (unsigned short*)(ws + OFF_KNN);            // 2,097,152
  unsigned short* knnL = (unsigned short*)(ws + OFF_KNN + 2097152);  // 2,097,152
  float*    h8   = (float*)(ws + OFF_H8);              // head (after gemm7)

  // catP lives at OFF_H8 from stage 1 (edge2 writes) through gemm7:
  unsigned short* catH = (unsigned short*)(ws + OFF_H8);             // 6,291,456
  unsigned short* catL = (unsigned short*)(ws + OFF_H8 + 6291456);   // 6,291,456
  // head-phase aliases (lifetimes disjoint):
  unsigned short* h7H  = (unsigned short*)(ws + OFF_H7);             // 16,777,216
  unsigned short* h7L  = (unsigned short*)(ws + OFF_H7 + 16777216);  // 16,777,216
  unsigned short* w6H  = (unsigned short*)(ws + OFF_CAT);            //   393,216
  unsigned short* w6L  = (unsigned short*)(ws + OFF_CAT + 393216);
  unsigned short* w7H  = (unsigned short*)(ws + OFF_CAT + 786432);   //   196,608
  unsigned short* w7L  = (unsigned short*)(ws + OFF_CAT + 983040);
  unsigned short* w8H  = (unsigned short*)(ws + OFF_CAT + 1179648);  //   262,144
  unsigned short* w8L  = (unsigned short*)(ws + OFF_CAT + 1441792);

  k_zero<<<32, 256, 0, stream>>>(glob);        // early; consumed by head phase

  // ---- stage 1 ----
  k_knn3<<<1024, 256, 0, stream>>>(x, idx);
  k_uv3<<<4096, 256, 0, stream>>>(x, w1, g15 + 0, v15 + 0, UV);
  k_edge2<<<2048, 256, 0, stream>>>(UV, idx, w2,
      g15 + 0,  b15 + 0,  m15 + 0,  v15 + 0,
      g15 + 64, b15 + 64, m15 + 64, v15 + 64, cat, 0, knnH, knnL, catH, catL, sq);

  // ---- stage 2 ----
  k_knn2p<<<2048, 256, 0, stream>>>(knnH, knnL, sq, pk);
  k_kmerge<<<256, 64, 0, stream>>>(pk, idx);
  dim3 guv(256, 2);
  k_uv<<<guv, 256, 0, stream>>>(cat, 192, 0, w3, g15 + 128, v15 + 128, UV);
  k_edge2<<<2048, 256, 0, stream>>>(UV, idx, w4,
      g15 + 128, b15 + 128, m15 + 128, v15 + 128,
      g15 + 192, b15 + 192, m15 + 192, v15 + 192, cat, 64, knnH, knnL, catH, catL, sq);

  // ---- stage 3 ----
  k_knn2p<<<2048, 256, 0, stream>>>(knnH, knnL, sq, pk);
  k_kmerge<<<256, 64, 0, stream>>>(pk, idx);
  k_uv<<<guv, 256, 0, stream>>>(cat, 192, 64, w5, g15 + 256, v15 + 256, UV);
  k_edge3<<<4096, 256, 0, stream>>>(UV, idx,
      g15 + 256, b15 + 256, m15 + 256, v15 + 256, cat, catH, catL);

  // ---- weight splits (cat packing fused into edge2/edge3) ----
  k_split<<<96, 256, 0, stream>>>(w6, 192, 0, 192, w6H, w6L);
  k_split<<<48, 256, 0, stream>>>(w7, 1216, 1024, 192, w7H, w7L);
  k_split<<<64, 256, 0, stream>>>(w8, 512, 0, 512, w8H, w8L);

  // ---- head (MFMA bf16x3, no-LDS K-loop) ----
  dim3 g6g(256, 16);
  k_gemm<EP_MAXGLOB><<<g6g, 256, 0, stream>>>(
      catH, catL, w6H, w6L, 192, g6, b6, m6, v6,
      nullptr, nullptr, 0, nullptr, nullptr, 0, glob);
  k_t7<<<4096, 64, 0, stream>>>(glob, w7, t7);
  dim3 g7g(256, 8);
  k_gemm<EP_BIAS_BNMISH><<<g7g, 256, 0, stream>>>(
      catH, catL, w7H, w7L, 192, g7, b7, m7, v7,
      t7, nullptr, 0, h7H, h7L, 512, nullptr);
  dim3 g8g(256, 4);
  k_gemm<EP_BNMISH><<<g8g, 256, 0, stream>>>(
      h7H, h7L, w8H, w8L, 512, g8, b8, m8, v8,
      nullptr, h8, 256, nullptr, nullptr, 0, nullptr);
  k_out<<<4096, 256, 0, stream>>>(h8, w9, (float*)d_out);
}

// Round 25
// 556.228 us; speedup vs baseline: 1.1202x; 1.0498x over previous
//
#include <hip/hip_runtime.h>
#include <math.h>

#define BN_EPS 1e-5f
typedef unsigned long long u64;
typedef __attribute__((ext_vector_type(8))) short bf16x8;
typedef __attribute__((ext_vector_type(8))) unsigned short u16x8;
typedef __attribute__((ext_vector_type(4))) float f32x4;

// mish(x) = x*tanh(ln(1+e^x)) = x*w/(w+2), w = u(u+2), u = e^x (clamped).
__device__ __forceinline__ float mishf(float x){
  float u = __expf(fminf(x, 20.f));
  float w = u * (u + 2.f);
  return x * w / (w + 2.f);
}

__device__ __forceinline__ unsigned fenc(float f){
  unsigned u = __float_as_uint(f);
  return u ^ ((unsigned)((int)u >> 31) | 0x80000000u);
}
__device__ __forceinline__ float fdec(unsigned e){
  unsigned u = (e & 0x80000000u) ? (e & 0x7fffffffu) : ~e;
  return __uint_as_float(u);
}

// bf16x3 split: a = hi + lo (+O(2^-17 a)); rne via bit trick
__device__ __forceinline__ void bfsplit(float a, unsigned short &h, unsigned short &l){
  unsigned u = __float_as_uint(a);
  unsigned hb = (u + 0x7FFFu + ((u >> 16) & 1u)) >> 16;
  h = (unsigned short)hb;
  float hf = __uint_as_float(hb << 16);
  float r = a - hf;
  unsigned v = __float_as_uint(r);
  l = (unsigned short)((v + 0x7FFFu + ((v >> 16) & 1u)) >> 16);
}

// packed key: (value desc, index asc) == lax.top_k order as single u64 compare
__device__ __forceinline__ u64 mkkey(float v, int i){
  return ((u64)fenc(v) << 32) | (unsigned)(~i);
}
__device__ __forceinline__ int keyidx(u64 k){ return (int)(~(unsigned)k); }

__device__ __forceinline__ void ins10k(u64 (&L)[10], u64 k){
  if (k <= L[9]) return;
  #pragma unroll
  for (int p = 9; p >= 1; --p)
    L[p] = (k > L[p-1]) ? L[p-1] : ((k > L[p]) ? k : L[p]);
  L[0] = (k > L[0]) ? k : L[0];
}

// branchless score-only insert into sorted-desc u32 list: 9x v_med3_u32 + max.
// Correct for all rank positions and duplicates (reads-before-writes preserved
// by the p=9..1 order). r22 lesson: the gated DUAL-list (score+index) push is
// wave-divergent and ~3x this cost per streamed cand -- score-only streaming +
// deferred survivor collection (two-pass) is the verified-fastest form.
__device__ __forceinline__ void ins10s(unsigned (&S)[10], unsigned e){
  #pragma unroll
  for (int p = 9; p >= 1; --p){
    unsigned ns;
    asm("v_med3_u32 %0, %1, %2, %3" : "=v"(ns) : "v"(e), "v"(S[p-1]), "v"(S[p]));
    S[p] = ns;
  }
  S[0] = (e > S[0]) ? e : S[0];
}

// snapshot-butterfly merge of sorted-desc lists across lanes differing in bit
// `mask`: snapshot partner's FULL list first (lockstep in-place merge would
// read a partially-merged partner list -> duplicates -> threshold too high).
__device__ __forceinline__ void wavemerge10(unsigned (&S)[10], int mask){
  unsigned T[10];
  #pragma unroll
  for (int j = 0; j < 10; ++j) T[j] = __shfl_xor(S[j], mask);
  #pragma unroll
  for (int j = 0; j < 10; ++j) ins10s(S, T[j]);
}
#define KSENT mkkey(-INFINITY, 0x7fffffff)

__global__ void k_diag(float* __restrict__ out, float v){ out[0] = v; }

__global__ __launch_bounds__(256)
void k_zero(unsigned* __restrict__ p){
  p[blockIdx.x * 256 + threadIdx.x] = 0u;      // 32 blocks -> 8192
}

// ---------- knn C=3 from x [B,3,N]: TWO-PASS, 16 points/block, 16 chunks ----------
// Pass 1: whole batch staged as float4(x,y,z,|x|^2) in LDS (padded stride 129);
// each lane streams 128 cands with a sorted u32 score list (9 med3 + max per
// cand). In-wave snapshot-butterfly merges the 4 chunks per wave; one LDS list
// per wave; t<16 merges 4 wave-lists -> exact 10th-best threshold per point.
// Pass 2: rescan from GLOBAL (bit-identical FMA chains), collect e>=thr
// survivors (<=16) via LDS counter; final 16-thread ins10k gives the exact
// (value desc, idx asc) order. Overlay aliases pts4 -> LDS stays 33KB.
__global__ __launch_bounds__(256)
void k_knn3(const float* __restrict__ x, int* __restrict__ idxout){
  __shared__ __align__(16) char smem[33024];
  float4* pts4   = (float4*)smem;                    // [16][129] (pass 1 only)
  unsigned* m1u  = (unsigned*)smem;                  // [4][10][16] = 2560 B
  unsigned* thr  = (unsigned*)(smem + 2560);         // [16]
  int*      cnt  = (int*)(smem + 2624);              // [16]
  u64*      buf  = (u64*)(smem + 2688);              // [16][16] = 2048 B
  const int t  = threadIdx.x;
  const int b  = blockIdx.x >> 7;                    // 1024 blocks: 128 per batch
  const int p0 = (blockIdx.x & 127) * 16;
  const int pt = t & 15, ch = t >> 4;
  const float* xb = x + (size_t)b * 6144;

  for (int i = t; i < 2048; i += 256) {
    float x0 = xb[i], x1 = xb[2048 + i], x2 = xb[4096 + i];
    float s2 = x0 * x0; s2 = fmaf(x1, x1, s2); s2 = fmaf(x2, x2, s2);
    pts4[(i >> 7) * 129 + (i & 127)] = make_float4(x0, x1, x2, s2);
  }
  __syncthreads();

  const int g = p0 + pt;
  const float4 ov = pts4[(g >> 7) * 129 + (g & 127)];
  unsigned S[10];
  #pragma unroll
  for (int j = 0; j < 10; ++j) S[j] = 0x007FFFFFu;   // fenc(-inf)
  const float4* cp = pts4 + ch * 129;
  #pragma unroll 4
  for (int j = 0; j < 128; ++j) {
    float4 pv = cp[j];
    float dot = ov.x * pv.x; dot = fmaf(ov.y, pv.y, dot); dot = fmaf(ov.z, pv.z, dot);
    float key = fmaf(2.f, dot, -ov.w) - pv.w;
    ins10s(S, fenc(key));
  }
  // merge the 4 chunks resident in this wave (lane bits 4,5 = ch&3)
  wavemerge10(S, 16);
  wavemerge10(S, 32);
  __syncthreads();                                   // pts4 reads done; overlay

  if ((t & 48) == 0) {                               // one lane per (wave, pt)
    int wv = t >> 6;
    #pragma unroll
    for (int j = 0; j < 10; ++j)
      m1u[(wv * 10 + j) * 16 + pt] = S[j];
  }
  __syncthreads();

  if (t < 16) {                                      // final threshold per point
    unsigned F[10];
    #pragma unroll
    for (int j = 0; j < 10; ++j) F[j] = 0x007FFFFFu;
    for (int wv = 0; wv < 4; ++wv)
      #pragma unroll
      for (int j = 0; j < 10; ++j)
        ins10s(F, m1u[(wv * 10 + j) * 16 + t]);
    thr[t] = F[9];
    cnt[t] = 0;
  }
  __syncthreads();

  // pass 2: rescan from global; recompute keys BIT-IDENTICALLY (same chains)
  const unsigned th = thr[pt];
  for (int j = 0; j < 128; ++j) {
    int c = ch * 128 + j;
    float x0 = xb[c], x1 = xb[2048 + c], x2 = xb[4096 + c];
    float s2 = x0 * x0; s2 = fmaf(x1, x1, s2); s2 = fmaf(x2, x2, s2);
    float dot = ov.x * x0; dot = fmaf(ov.y, x1, dot); dot = fmaf(ov.z, x2, dot);
    float key = fmaf(2.f, dot, -ov.w) - s2;
    unsigned e = fenc(key);
    if (e >= th) {
      int slot = atomicAdd(&cnt[pt], 1);
      if (slot < 16) buf[pt * 16 + slot] = ((u64)e << 32) | (unsigned)(~c);
    }
  }
  __syncthreads();

  if (t < 16) {
    u64 F[10];
    #pragma unroll
    for (int j = 0; j < 10; ++j) F[j] = KSENT;
    int n = cnt[t]; n = (n < 16) ? n : 16;
    for (int e2 = 0; e2 < n; ++e2) ins10k(F, buf[t * 16 + e2]);
    #pragma unroll
    for (int j = 0; j < 10; ++j)
      idxout[(size_t)(b * 2048 + p0 + t) * 10 + j] = keyidx(F[j]);
  }
}

// ---------- knn C=64 partial, MFMA bf16x3, KEY-CACHED TWO-PASS ----------
// 64 query rows x 256 cands/block (8-way split); frag-packed input (K=64).
// Pass 1: MFMA scores with the m0 loop FULLY unrolled; each lane's 64 encoded
// keys are kept in VGPRs (compile-time indices -> registers, no scratch).
// Dual score lists (S0/S1) + union-merge + in-wave butterfly give the exact
// per-qrow threshold in register, as before.
// Pass 2: NO recompute -- iterate the 64 cached keys, gated append of
// survivors (cand index derived from register position). (r24: landed,
// knn2p dropped out of the top-5.)
__global__ __launch_bounds__(256)
void k_knn2p(const unsigned short* __restrict__ H, const unsigned short* __restrict__ Lp,
             const float* __restrict__ sq, u64* __restrict__ pk){
  __shared__ __align__(16) char smem[9472];
  float*    ssB = (float*)smem;                  // [256] @0 (pass 1 only)
  int*      cnt = (int*)(smem + 1024);           // [64]
  u64*      buf = (u64*)(smem + 1280);           // [64][16] = 8192 -> 9472

  const int t  = threadIdx.x;
  const int bx = blockIdx.x;
  const int cc = bx & 7;
  const int rg = (bx >> 3) & 31;
  const int b  = bx >> 8;
  const int p0 = rg * 64;
  const int c0 = cc * 256;
  const int lane = t & 63, w = t >> 6;
  const int la  = (lane & 15) * 8;
  const int sub = lane >> 4;                 // k-chunk of frags == cand sub-block
  const int qrow = w * 16 + (lane & 15);     // this lane's query row (0..63)

  // query fragments (second operand): rows b*2048+p0+w*16..+15, K=64
  const size_t ag = ((size_t)((b * 2048 + p0) >> 4) + w) * 8 + sub;
  bf16x8 aH0 = *(const bf16x8*)&H [ ag      * 128 + la];
  bf16x8 aL0 = *(const bf16x8*)&Lp[ ag      * 128 + la];
  bf16x8 aH1 = *(const bf16x8*)&H [(ag + 4) * 128 + la];
  bf16x8 aL1 = *(const bf16x8*)&Lp[(ag + 4) * 128 + la];

  ssB[t] = sq[b * 2048 + c0 + (t & 255)];
  if (t < 64) cnt[t] = 0;
  const float nsA = -sq[b * 2048 + p0 + qrow];

  unsigned S0[10], S1[10];
  unsigned keys[64];
  #pragma unroll
  for (int j = 0; j < 10; ++j) { S0[j] = 0x007FFFFFu; S1[j] = 0x007FFFFFu; }
  __syncthreads();

  // ---- pass 1: score + key-cache (fully unrolled -> keys[] in registers) ----
  #pragma unroll
  for (int m0i = 0; m0i < 4; ++m0i) {
    const size_t cgb = ((size_t)((b * 2048 + c0 + m0i * 64) >> 4)) * 8 + sub;
    #pragma unroll
    for (int tile = 0; tile < 4; ++tile) {
      const size_t cg = (cgb + (size_t)tile * 8) * 128 + la;
      bf16x8 bH0 = *(const bf16x8*)&H [cg];
      bf16x8 bL0 = *(const bf16x8*)&Lp[cg];
      bf16x8 bH1 = *(const bf16x8*)&H [cg + 512];
      bf16x8 bL1 = *(const bf16x8*)&Lp[cg + 512];
      f32x4 acc = {0.f, 0.f, 0.f, 0.f};
      acc = __builtin_amdgcn_mfma_f32_16x16x32_bf16(bH0, aL0, acc, 0, 0, 0);
      acc = __builtin_amdgcn_mfma_f32_16x16x32_bf16(bL0, aH0, acc, 0, 0, 0);
      acc = __builtin_amdgcn_mfma_f32_16x16x32_bf16(bH0, aH0, acc, 0, 0, 0);
      acc = __builtin_amdgcn_mfma_f32_16x16x32_bf16(bH1, aL1, acc, 0, 0, 0);
      acc = __builtin_amdgcn_mfma_f32_16x16x32_bf16(bL1, aH1, acc, 0, 0, 0);
      acc = __builtin_amdgcn_mfma_f32_16x16x32_bf16(bH1, aH1, acc, 0, 0, 0);
      float4 s4 = *(const float4*)&ssB[m0i * 64 + tile * 16 + sub * 4];
      unsigned e0 = fenc(fmaf(2.f, acc[0], nsA) - s4.x);
      unsigned e1 = fenc(fmaf(2.f, acc[1], nsA) - s4.y);
      unsigned e2 = fenc(fmaf(2.f, acc[2], nsA) - s4.z);
      unsigned e3 = fenc(fmaf(2.f, acc[3], nsA) - s4.w);
      keys[m0i * 16 + tile * 4 + 0] = e0;
      keys[m0i * 16 + tile * 4 + 1] = e1;
      keys[m0i * 16 + tile * 4 + 2] = e2;
      keys[m0i * 16 + tile * 4 + 3] = e3;
      ins10s(S0, e0);
      ins10s(S1, e1);
      ins10s(S0, e2);
      ins10s(S1, e3);
    }
  }
  #pragma unroll
  for (int j = 0; j < 10; ++j) ins10s(S0, S1[j]);    // exact union top-10

  // in-wave merge across the 4 sub-lanes of each qrow -> threshold in register
  wavemerge10(S0, 16);
  wavemerge10(S0, 32);
  const unsigned thq = S0[9];

  // ---- pass 2: cached keys, gated append of survivors (no recompute) ----
  #pragma unroll
  for (int q = 0; q < 64; ++q) {
    unsigned e = keys[q];
    if (e >= thq) {
      int cand = c0 + (q >> 4) * 64 + ((q >> 2) & 3) * 16 + sub * 4 + (q & 3);
      int slot = atomicAdd(&cnt[qrow], 1);
      if (slot < 16) buf[qrow * 16 + slot] = ((u64)e << 32) | (unsigned)(~cand);
    }
  }
  __syncthreads();

  if (t < 64) {
    u64 F[10];
    #pragma unroll
    for (int j = 0; j < 10; ++j) F[j] = KSENT;
    int n = cnt[t]; n = (n < 16) ? n : 16;
    for (int e2 = 0; e2 < n; ++e2) ins10k(F, buf[t * 16 + e2]);
    size_t base = (size_t)(b * 2048 + p0 + t) * 80 + cc * 10;
    #pragma unroll
    for (int j = 0; j < 10; ++j) pk[base + j] = F[j];
  }
}

// ---------- merge 8 partial top-10 key lists -> final idx ----------
__global__ __launch_bounds__(64)
void k_kmerge(const u64* __restrict__ pk, int* __restrict__ idxout){
  int row = blockIdx.x * 64 + threadIdx.x;     // 256 blocks -> 16384
  u64 F[10];
  #pragma unroll
  for (int j = 0; j < 10; ++j) F[j] = KSENT;
  size_t base = (size_t)row * 80;
  for (int e = 0; e < 80; ++e) ins10k(F, pk[base + e]);
  #pragma unroll
  for (int j = 0; j < 10; ++j) idxout[(size_t)row * 10 + j] = keyidx(F[j]);
}

// ---------- UV for stage 1 (C=3): elementwise, reads x [B,3,N] directly ----------
__global__ __launch_bounds__(256)
void k_uv3(const float* __restrict__ x, const float* __restrict__ w1,
           const float* __restrict__ gg, const float* __restrict__ vv,
           float* __restrict__ UV){
  int i = blockIdx.x * 256 + threadIdx.x;      // 4096 blocks
  int p = i >> 6, o = i & 63;
  int b = p >> 11, n = p & 2047;
  float s = gg[o] / sqrtf(vv[o] + BN_EPS);
  const float* xb = x + (size_t)b * 6144 + n;
  float x0 = xb[0], x1 = xb[2048], x2 = xb[4096];
  const float* wr = w1 + o * 6;
  float u = s * (wr[0] * x0 + wr[1] * x1 + wr[2] * x2);
  float v = s * ((wr[3] - wr[0]) * x0 + (wr[4] - wr[1]) * x1 + (wr[5] - wr[2]) * x2);
  UV[(size_t)p * 128 + o] = u;
  UV[(size_t)p * 128 + 64 + o] = v;
}

// ---------- UV for stages 2/3 (C=64): tiled GEMM, s1 folded ----------
__global__ __launch_bounds__(256)
void k_uv(const float* __restrict__ A, int lda, int aoff,
          const float* __restrict__ w,       // [64][128]
          const float* __restrict__ gg, const float* __restrict__ vv,
          float* __restrict__ UV){
  __shared__ float As[16][68];
  __shared__ float Bs[16][68];
  __shared__ float ss[64];
  const int t = threadIdx.x;
  const int tx = t & 15, ty = t >> 4;
  const int m0 = blockIdx.x * 64;
  const int half = blockIdx.y;
  if (t < 64) ss[t] = gg[t] / sqrtf(vv[t] + BN_EPS);
  __syncthreads();
  float acc[4][4] = {};
  for (int k0 = 0; k0 < 64; k0 += 16) {
    for (int i = t; i < 1024; i += 256) {
      int m = i >> 4, k = i & 15;
      As[k][m] = A[(size_t)(m0 + m) * lda + aoff + k0 + k];
    }
    for (int i = t; i < 1024; i += 256) {
      int n = i >> 4, k = i & 15;
      int kk = k0 + k;
      float wv = half ? (w[n * 128 + 64 + kk] - w[n * 128 + kk]) : w[n * 128 + kk];
      Bs[k][n] = wv * ss[n];
    }
    __syncthreads();
    #pragma unroll
    for (int k = 0; k < 16; ++k) {
      float4 a4 = *(const float4*)&As[k][tx * 4];
      float4 b4 = *(const float4*)&Bs[k][ty * 4];
      float am[4] = {a4.x, a4.y, a4.z, a4.w};
      float bm[4] = {b4.x, b4.y, b4.z, b4.w};
      #pragma unroll
      for (int q = 0; q < 4; ++q)
        #pragma unroll
        for (int r = 0; r < 4; ++r)
          acc[q][r] = fmaf(am[q], bm[r], acc[q][r]);
    }
    __syncthreads();
  }
  #pragma unroll
  for (int q = 0; q < 4; ++q)
    #pragma unroll
    for (int r = 0; r < 4; ++r)
      UV[(size_t)(m0 + tx * 4 + q) * 128 + half * 64 + ty * 4 + r] = acc[q][r];
}

// ---------- edge stage with conv2: 8 points/block, grid 2048 ----------
// emits max-pooled output to cat f32, frag-packed bf16 K=64 (kH/kL for knn),
// frag-packed bf16 K=192 (cH/cL for head GEMMs -- replaces k_split(cat)),
// and |.|^2 (sqout). The bfsplit is computed ONCE and reused for both packings.
__global__ __launch_bounds__(256)
void k_edge2(const float* __restrict__ UV, const int* __restrict__ idx,
             const float* __restrict__ w2,   // [64][64]
             const float* __restrict__ g1, const float* __restrict__ b1,
             const float* __restrict__ m1, const float* __restrict__ v1,
             const float* __restrict__ g2, const float* __restrict__ b2,
             const float* __restrict__ m2, const float* __restrict__ v2,
             float* __restrict__ cat, int coff,
             unsigned short* __restrict__ kH, unsigned short* __restrict__ kL,
             unsigned short* __restrict__ cH, unsigned short* __restrict__ cL,
             float* __restrict__ sqout){
  __shared__ float Ha[64][81];
  __shared__ float Ws[64][68];
  __shared__ float o1s[64], s2s[64], o2s[64];
  __shared__ int   ejs[80];
  const int t = threadIdx.x;
  const int p0 = blockIdx.x * 8;  // 2048 blocks
  const int batch = p0 >> 11;
  if (t < 80) ejs[t] = batch * 2048 + (idx[p0 * 10 + t] & 2047);
  if (t < 64) {
    float s1 = g1[t] / sqrtf(v1[t] + BN_EPS);
    o1s[t] = b1[t] - m1[t] * s1;
    float s2 = g2[t] / sqrtf(v2[t] + BN_EPS);
    s2s[t] = s2;
    o2s[t] = b2[t] - m2[t] * s2;
  }
  for (int i = t; i < 4096; i += 256) {
    int k = i & 63, n = i >> 6;
    Ws[k][n] = w2[n * 64 + k];
  }
  __syncthreads();

  for (int i = t; i < 5120; i += 256) {
    int e = i >> 6, c = i & 63;
    int p = p0 + e / 10;
    float hv = UV[(size_t)ejs[e] * 128 + c] + UV[(size_t)p * 128 + 64 + c] + o1s[c];
    Ha[c][e] = mishf(hv);
  }
  __syncthreads();

  const int tx = t & 15, ty = t >> 4;
  float acc[5][4] = {};
  #pragma unroll 8
  for (int k = 0; k < 64; ++k) {
    float av[5];
    #pragma unroll
    for (int i2 = 0; i2 < 5; ++i2) av[i2] = Ha[k][tx * 5 + i2];
    float4 b4 = *(const float4*)&Ws[k][ty * 4];
    float bv[4] = {b4.x, b4.y, b4.z, b4.w};
    #pragma unroll
    for (int i2 = 0; i2 < 5; ++i2)
      #pragma unroll
      for (int r = 0; r < 4; ++r)
        acc[i2][r] = fmaf(av[i2], bv[r], acc[i2][r]);
  }
  __syncthreads();
  #pragma unroll
  for (int i2 = 0; i2 < 5; ++i2)
    #pragma unroll
    for (int r = 0; r < 4; ++r) {
      int o = ty * 4 + r;
      Ha[o][tx * 5 + i2] = mishf(acc[i2][r] * s2s[o] + o2s[o]);
    }
  __syncthreads();

  for (int i = t; i < 512; i += 256) {
    int p = i >> 6, o = i & 63;
    float mx = Ha[o][p * 10];
    #pragma unroll
    for (int k = 1; k < 10; ++k) mx = fmaxf(mx, Ha[o][p * 10 + k]);
    cat[(size_t)(p0 + p) * 192 + coff + o] = mx;
    unsigned short hh, ll;
    bfsplit(mx, hh, ll);
    int n = p0 + p;
    size_t pos = ((size_t)(n >> 4) * 8 + (o >> 3)) * 128 + (n & 15) * 8 + (o & 7);
    kH[pos] = hh; kL[pos] = ll;
    int kk = coff + o;                       // K=192 packing (head GEMM input)
    size_t pos192 = ((size_t)(n >> 4) * 24 + (kk >> 3)) * 128 + (n & 15) * 8 + (kk & 7);
    cH[pos192] = hh; cL[pos192] = ll;
    // fused |.|^2: wave covers exactly the 64 channels of one point
    float r = mx * mx;
    #pragma unroll
    for (int m = 32; m; m >>= 1) r += __shfl_xor(r, m);
    if (o == 0) sqout[p0 + p] = r;
  }
}

// ---------- edge stage 3 (no conv2): also emits K=192 packed bf16 ----------
__global__ __launch_bounds__(256)
void k_edge3(const float* __restrict__ UV, const int* __restrict__ idx,
             const float* __restrict__ gg, const float* __restrict__ bb,
             const float* __restrict__ mn, const float* __restrict__ vv,
             float* __restrict__ cat,
             unsigned short* __restrict__ cH, unsigned short* __restrict__ cL){
  int i = blockIdx.x * 256 + threadIdx.x;      // 4096 blocks
  int p = i >> 6, o = i & 63;
  int batch = p >> 11;
  float s = gg[o] / sqrtf(vv[o] + BN_EPS);
  float of = bb[o] - mn[o] * s;
  float v_ = UV[(size_t)p * 128 + 64 + o] + of;
  float mx = -INFINITY;
  #pragma unroll
  for (int k = 0; k < 10; ++k) {
    int j = batch * 2048 + (idx[p * 10 + k] & 2047);
    mx = fmaxf(mx, mishf(UV[(size_t)j * 128 + o] + v_));
  }
  cat[(size_t)p * 192 + 128 + o] = mx;
  unsigned short hh, ll;
  bfsplit(mx, hh, ll);
  int kk = 128 + o;
  size_t pos192 = ((size_t)(p >> 4) * 24 + (kk >> 3)) * 128 + (p & 15) * 8 + (kk & 7);
  cH[pos192] = hh; cL[pos192] = ll;
}

// ---------- split src[N][K] -> frag-packed bf16 hi/lo, 8 elems/thread ----------
// pos = ((n>>4)*(K/8) + (k>>3))*128 + (n&15)*8 + (k&7); coalesced 16B writes
// (weights only now; cat packing fused into edge2/edge3)
__global__ __launch_bounds__(256)
void k_split(const float* __restrict__ src, int ld, int koff, int K,
             unsigned short* __restrict__ H, unsigned short* __restrict__ L){
  int i = blockIdx.x * 256 + threadIdx.x;      // one per 8 elements
  int kg = K >> 3;
  int n = i / kg, g = i - n * kg;
  const float* s = &src[(size_t)n * ld + koff + g * 8];
  float4 v0 = *(const float4*)s, v1 = *(const float4*)(s + 4);
  float vv[8] = {v0.x, v0.y, v0.z, v0.w, v1.x, v1.y, v1.z, v1.w};
  u16x8 hh, ll;
  #pragma unroll
  for (int q = 0; q < 8; ++q) {
    unsigned short h_, l_;
    bfsplit(vv[q], h_, l_);
    hh[q] = h_; ll[q] = l_;
  }
  size_t pos = ((size_t)(n >> 4) * kg + g) * 128 + (n & 15) * 8;
  *(u16x8*)&H[pos] = hh;
  *(u16x8*)&L[pos] = ll;
}

// ---------- MFMA bf16x3 head GEMM: 64x64 tile, frags direct from global ----------
#define EP_BNMISH      0
#define EP_MAXGLOB     1
#define EP_BIAS_BNMISH 2

template<int EPI>
__global__ __launch_bounds__(256)
void k_gemm(const unsigned short* __restrict__ APH, const unsigned short* __restrict__ APL,
            const unsigned short* __restrict__ WPH, const unsigned short* __restrict__ WPL,
            int K,
            const float* __restrict__ gg, const float* __restrict__ bb,
            const float* __restrict__ mn, const float* __restrict__ vv,
            const float* __restrict__ bias,
            float* __restrict__ out, int ldo,
            unsigned short* __restrict__ oH, unsigned short* __restrict__ oL, int oldo,
            unsigned* __restrict__ glob)
{
  __shared__ float red[64][17];
  const int t = threadIdx.x;
  const int lane = t & 63, w = t >> 6;
  const int m0 = blockIdx.x * 64, n0 = blockIdx.y * 64;
  const int kg = K >> 3;
  const int la = (lane & 15) * 8;
  f32x4 acc[4] = {{0,0,0,0},{0,0,0,0},{0,0,0,0},{0,0,0,0}};
  const size_t abase = ((size_t)((m0 >> 4) + w) * kg + (lane >> 4)) * 128 + la;

  for (int k0 = 0; k0 < K; k0 += 32) {
    size_t ao = abase + (size_t)(k0 >> 3) * 128;
    bf16x8 aH = *(const bf16x8*)&APH[ao];
    bf16x8 aL = *(const bf16x8*)&APL[ao];
    #pragma unroll
    for (int tt = 0; tt < 4; ++tt) {
      size_t wo = ((size_t)((n0 >> 4) + tt) * kg + (k0 >> 3) + (lane >> 4)) * 128 + la;
      bf16x8 bH = *(const bf16x8*)&WPH[wo];
      bf16x8 bL = *(const bf16x8*)&WPL[wo];
      acc[tt] = __builtin_amdgcn_mfma_f32_16x16x32_bf16(aL, bH, acc[tt], 0, 0, 0);
      acc[tt] = __builtin_amdgcn_mfma_f32_16x16x32_bf16(aH, bL, acc[tt], 0, 0, 0);
      acc[tt] = __builtin_amdgcn_mfma_f32_16x16x32_bf16(aH, bH, acc[tt], 0, 0, 0);
    }
  }

  const int mrow = m0 + w * 16 + ((lane >> 4) << 2);   // C/D: row=(lane>>4)*4+reg
  const int batch = m0 >> 11;

  if (EPI == EP_MAXGLOB) {
    #pragma unroll
    for (int tt = 0; tt < 4; ++tt) {
      int nn = n0 + tt * 16 + (lane & 15);
      float s = gg[nn] / sqrtf(vv[nn] + BN_EPS);
      float f = bb[nn] - mn[nn] * s;
      float mx = -INFINITY;
      #pragma unroll
      for (int r = 0; r < 4; ++r) mx = fmaxf(mx, mishf(acc[tt][r] * s + f));
      red[tt * 16 + (lane & 15)][w * 4 + (lane >> 4)] = mx;
    }
    __syncthreads();
    if (t < 64) {
      float v = red[t][0];
      #pragma unroll
      for (int q = 1; q < 16; ++q) v = fmaxf(v, red[t][q]);
      atomicMax(&glob[batch * 1024 + n0 + t], fenc(v));
    }
  } else {
    #pragma unroll
    for (int tt = 0; tt < 4; ++tt) {
      int nn = n0 + tt * 16 + (lane & 15);
      float s = gg[nn] / sqrtf(vv[nn] + BN_EPS);
      float f = bb[nn] - mn[nn] * s;
      float bv = (EPI == EP_BIAS_BNMISH) ? bias[batch * 512 + nn] : 0.f;
      #pragma unroll
      for (int r = 0; r < 4; ++r) {
        int m = mrow + r;
        float h = mishf((acc[tt][r] + bv) * s + f);
        if (EPI == EP_BIAS_BNMISH) {
          unsigned short hh, ll;
          bfsplit(h, hh, ll);
          size_t pos = ((size_t)(m >> 4) * (oldo >> 3) + (nn >> 3)) * 128
                       + (m & 15) * 8 + (nn & 7);
          oH[pos] = hh; oL[pos] = ll;
        } else {
          out[(size_t)m * ldo + nn] = h;
        }
      }
    }
  }
}

// ---------- t7[b][o] = w7[o, :1024] . glob[b]: one wave per output ----------
// grid 4096 (b*512+o), 64 threads; lane j sums c = j, j+64, ... (coalesced),
// then shfl_xor tree reduce. Replaces 16-block serial/uncoalesced version.
__global__ __launch_bounds__(64)
void k_t7(const unsigned* __restrict__ glob, const float* __restrict__ w7,
          float* __restrict__ t7){
  int bo = blockIdx.x;                         // 4096
  int b = bo >> 9, o = bo & 511;
  int j = threadIdx.x;
  const float* wr = w7 + (size_t)o * 1216;
  const unsigned* gr = glob + b * 1024;
  float acc = 0.f;
  #pragma unroll
  for (int c = j; c < 1024; c += 64)
    acc = fmaf(wr[c], fdec(gr[c]), acc);
  #pragma unroll
  for (int m = 32; m; m >>= 1) acc += __shfl_xor(acc, m);
  if (j == 0) t7[bo] = acc;
}

// ---------- final conv: wave-per-point, full-lane K-parallel ----------
// (r25: old form had 18/64 lanes on a 256-deep serial fmaf chain -> 56us,
// ~19x off the memory roofline, HBM 191 GB/s. Now: lane j holds channels
// {j, j+64, j+128, j+192} via 4 coalesced loads; 18 accumulators x 4 fmaf
// (chain depth 4, 18-way ILP); 6-step shfl_xor butterfly reduces all 18;
// compile-time select chain routes output o to lane o (static register
// indices, rule #20). No LDS. w9 (18KB) stays L1-resident.)
__global__ __launch_bounds__(256)
void k_out(const float* __restrict__ h8, const float* __restrict__ w9,
           float* __restrict__ out)
{
  const int t = threadIdx.x;
  const int wv = t >> 6, j = t & 63;
  const int p = blockIdx.x * 4 + wv;           // 4096 blocks
  const float* hp = h8 + (size_t)p * 256;
  float h0 = hp[j], h1 = hp[j + 64], h2 = hp[j + 128], h3 = hp[j + 192];
  float acc[18];
  #pragma unroll
  for (int o = 0; o < 18; ++o) {
    const float* wr = w9 + o * 256 + j;
    float a = wr[0] * h0;
    a = fmaf(wr[64],  h1, a);
    a = fmaf(wr[128], h2, a);
    a = fmaf(wr[192], h3, a);
    acc[o] = a;
  }
  #pragma unroll
  for (int m = 32; m; m >>= 1)
    #pragma unroll
    for (int o = 0; o < 18; ++o)
      acc[o] += __shfl_xor(acc[o], m);
  float myval = 0.f;
  #pragma unroll
  for (int o = 0; o < 18; ++o) myval = (j == o) ? acc[o] : myval;
  if (j < 18) {
    int b = p >> 11, n = p & 2047;
    out[(size_t)b * 36864 + j * 2048 + n] = myval;
  }
}

extern "C" void kernel_launch(void* const* d_in, const int* in_sizes, int n_in,
                              void* d_out, int out_size, void* d_ws, size_t ws_size,
                              hipStream_t stream)
{
  // Layout (stage phase): sq@0 (64KB, in the region freed when k_cast died),
  // idx@256K, cat f32@OFF_CAT, glob, t7, UV@OFF_H7 (8.4M), knnP@+8.4M (4M),
  // pk@+12.6M (10.5M, ends 36.6M < OFF_H8), catP@OFF_H8 (12.6M, written by
  // edge2/edge3, live until gemm7). Head: W-splits alias OFF_CAT (cat dead),
  // h7P@OFF_H7 (33.5M, overwrites UV/knnP/pk -- all dead), h8@OFF_H8
  // (overwrites catP after gemm7 consumed it).
  const size_t OFF_IDX  = 262144;
  const size_t OFF_CAT  = 917504;
  const size_t OFF_GLOB = 13500416;
  const size_t OFF_T7   = 13533184;
  const size_t OFF_H7   = 13549568;
  const size_t OFF_KNN  = OFF_H7 + 8388608;
  const size_t OFF_PK   = OFF_H7 + 12582912;   // ends 36,618,240 < OFF_H8
  const size_t OFF_H8   = 47104000;
  const size_t NEED     = 63881216;

  static const int EXP[26] = {
    49152, 384, 4096, 8192, 4096, 8192, 196608, 622592, 131072, 4608,
    320, 320, 320, 320, 1024, 1024, 1024, 1024,
    512, 512, 512, 512, 256, 256, 256, 256 };
  if (n_in < 26) { k_diag<<<1,1,0,stream>>>((float*)d_out, 16384.f); return; }
  for (int i = 0; i < 26; ++i)
    if (in_sizes[i] != EXP[i]) {
      k_diag<<<1,1,0,stream>>>((float*)d_out, 4096.f + 128.f * i); return;
    }
  if (out_size != 294912) { k_diag<<<1,1,0,stream>>>((float*)d_out, 20480.f); return; }
  if (ws_size < NEED) {
    k_diag<<<1,1,0,stream>>>((float*)d_out, 24576.f + (float)(ws_size >> 20)); return;
  }

  const float* x  = (const float*)d_in[0];
  const float* w1 = (const float*)d_in[1];
  const float* w2 = (const float*)d_in[2];
  const float* w3 = (const float*)d_in[3];
  const float* w4 = (const float*)d_in[4];
  const float* w5 = (const float*)d_in[5];
  const float* w6 = (const float*)d_in[6];
  const float* w7 = (const float*)d_in[7];
  const float* w8 = (const float*)d_in[8];
  const float* w9 = (const float*)d_in[9];
  const float* g15 = (const float*)d_in[10];
  const float* b15 = (const float*)d_in[11];
  const float* m15 = (const float*)d_in[12];
  const float* v15 = (const float*)d_in[13];
  const float* g6 = (const float*)d_in[14];
  const float* b6 = (const float*)d_in[15];
  const float* m6 = (const float*)d_in[16];
  const float* v6 = (const float*)d_in[17];
  const float* g7 = (const float*)d_in[18];
  const float* b7 = (const float*)d_in[19];
  const float* m7 = (const float*)d_in[20];
  const float* v7 = (const float*)d_in[21];
  const float* g8 = (const float*)d_in[22];
  const float* b8 = (const float*)d_in[23];
  const float* m8 = (const float*)d_in[24];
  const float* v8 = (const float*)d_in[25];

  char* ws = (char*)d_ws;
  float*    sq   = (float*)(ws + 0);                   // 65,536 (stages)
  int*      idx  = (int*)(ws + OFF_IDX);
  float*    cat  = (float*)(ws + OFF_CAT);
  unsigned* glob = (unsigned*)(ws + OFF_GLOB);
  float*    t7   = (float*)(ws + OFF_T7);
  float*    UV   = (float*)(ws + OFF_H7);
  u64*      pk   = (u64*)(ws + OFF_PK);                // 10,485,760 (stages)
  unsigned short* knnH = (unsigned short*)(ws + OFF_KNN);            // 2,097,152
  unsigned short* knnL = (unsigned short*)(ws + OFF_KNN + 2097152);  // 2,097,152
  float*    h8   = (float*)(ws + OFF_H8);              // head (after gemm7)

  // catP lives at OFF_H8 from stage 1 (edge2 writes) through gemm7:
  unsigned short* catH = (unsigned short*)(ws + OFF_H8);             // 6,291,456
  unsigned short* catL = (unsigned short*)(ws + OFF_H8 + 6291456);   // 6,291,456
  // head-phase aliases (lifetimes disjoint):
  unsigned short* h7H  = (unsigned short*)(ws + OFF_H7);             // 16,777,216
  unsigned short* h7L  = (unsigned short*)(ws + OFF_H7 + 16777216);  // 16,777,216
  unsigned short* w6H  = (unsigned short*)(ws + OFF_CAT);            //   393,216
  unsigned short* w6L  = (unsigned short*)(ws + OFF_CAT + 393216);
  unsigned short* w7H  = (unsigned short*)(ws + OFF_CAT + 786432);   //   196,608
  unsigned short* w7L  = (unsigned short*)(ws + OFF_CAT + 983040);
  unsigned short* w8H  = (unsigned short*)(ws + OFF_CAT + 1179648);  //   262,144
  unsigned short* w8L  = (unsigned short*)(ws + OFF_CAT + 1441792);

  k_zero<<<32, 256, 0, stream>>>(glob);        // early; consumed by head phase

  // ---- stage 1 ----
  k_knn3<<<1024, 256, 0, stream>>>(x, idx);
  k_uv3<<<4096, 256, 0, stream>>>(x, w1, g15 + 0, v15 + 0, UV);
  k_edge2<<<2048, 256, 0, stream>>>(UV, idx, w2,
      g15 + 0,  b15 + 0,  m15 + 0,  v15 + 0,
      g15 + 64, b15 + 64, m15 + 64, v15 + 64, cat, 0, knnH, knnL, catH, catL, sq);

  // ---- stage 2 ----
  k_knn2p<<<2048, 256, 0, stream>>>(knnH, knnL, sq, pk);
  k_kmerge<<<256, 64, 0, stream>>>(pk, idx);
  dim3 guv(256, 2);
  k_uv<<<guv, 256, 0, stream>>>(cat, 192, 0, w3, g15 + 128, v15 + 128, UV);
  k_edge2<<<2048, 256, 0, stream>>>(UV, idx, w4,
      g15 + 128, b15 + 128, m15 + 128, v15 + 128,
      g15 + 192, b15 + 192, m15 + 192, v15 + 192, cat, 64, knnH, knnL, catH, catL, sq);

  // ---- stage 3 ----
  k_knn2p<<<2048, 256, 0, stream>>>(knnH, knnL, sq, pk);
  k_kmerge<<<256, 64, 0, stream>>>(pk, idx);
  k_uv<<<guv, 256, 0, stream>>>(cat, 192, 64, w5, g15 + 256, v15 + 256, UV);
  k_edge3<<<4096, 256, 0, stream>>>(UV, idx,
      g15 + 256, b15 + 256, m15 + 256, v15 + 256, cat, catH, catL);

  // ---- weight splits (cat packing fused into edge2/edge3) ----
  k_split<<<96, 256, 0, stream>>>(w6, 192, 0, 192, w6H, w6L);
  k_split<<<48, 256, 0, stream>>>(w7, 1216, 1024, 192, w7H, w7L);
  k_split<<<64, 256, 0, stream>>>(w8, 512, 0, 512, w8H, w8L);

  // ---- head (MFMA bf16x3, no-LDS K-loop) ----
  dim3 g6g(256, 16);
  k_gemm<EP_MAXGLOB><<<g6g, 256, 0, stream>>>(
      catH, catL, w6H, w6L, 192, g6, b6, m6, v6,
      nullptr, nullptr, 0, nullptr, nullptr, 0, glob);
  k_t7<<<4096, 64, 0, stream>>>(glob, w7, t7);
  dim3 g7g(256, 8);
  k_gemm<EP_BIAS_BNMISH><<<g7g, 256, 0, stream>>>(
      catH, catL, w7H, w7L, 192, g7, b7, m7, v7,
      t7, nullptr, 0, h7H, h7L, 512, nullptr);
  dim3 g8g(256, 4);
  k_gemm<EP_BNMISH><<<g8g, 256, 0, stream>>>(
      h7H, h7L, w8H, w8L, 512, g8, b8, m8, v8,
      nullptr, h8, 256, nullptr, nullptr, 0, nullptr);
  k_out<<<4096, 256, 0, stream>>>(h8, w9, (float*)d_out);
}